// Round 12
// baseline (1450.315 us; speedup 1.0000x reference)
//
#include <hip/hip_runtime.h>
#include <hip/hip_bf16.h>

// Problem constants
#define B 128
#define S 196
#define E 2048
#define D 512
#define A 256
#define V 10000
#define EM 512
#define T 20
#define KCAT 2560         // ctx(2048) + h(512) concatenated K for gates

typedef unsigned short u16;
typedef __bf16 bf16x8 __attribute__((ext_vector_type(8)));
typedef float f32x4 __attribute__((ext_vector_type(4)));
typedef u16 u16x8 __attribute__((ext_vector_type(8)));
typedef u16 u16x4 __attribute__((ext_vector_type(4)));

__device__ inline u16 f2bf(float f) {
    union { float f; unsigned u; } x; x.f = f;
    return (u16)((x.u + 0x7FFFu + ((x.u >> 16) & 1u)) >> 16);
}
__device__ inline float bf2f(u16 h) {
    union { unsigned u; float f; } x; x.u = ((unsigned)h) << 16;
    return x.f;
}
__device__ inline bf16x8 ld_bf8(const u16* p) {
    return __builtin_bit_cast(bf16x8, *reinterpret_cast<const u16x8*>(p));
}
__device__ inline bf16x8 cvt_bf8(const float* p) {
    float4 u = *reinterpret_cast<const float4*>(p);
    float4 v = *reinterpret_cast<const float4*>(p + 4);
    u16x8 t;
    t[0] = f2bf(u.x); t[1] = f2bf(u.y); t[2] = f2bf(u.z); t[3] = f2bf(u.w);
    t[4] = f2bf(v.x); t[5] = f2bf(v.y); t[6] = f2bf(v.z); t[7] = f2bf(v.w);
    return __builtin_bit_cast(bf16x8, t);
}
__device__ inline float sigm(float x) { return 1.f / (1.f + expf(-x)); }

// ===========================================================================
// Generic streaming MFMA bf16 GEMM (no LDS).
// ===========================================================================
struct PairT {
    const void* Ap;  // bf16 (u16*) or float* when AF32
    long lda;
    const u16* Bt;   // B^T [Npad][K] bf16
    long ldb;
    int K;           // multiple of 32
};

template <int NP, bool AF32, typename OutT, int WTM, int WTN, int WVM, int WVN,
          bool SWAPXY = false>
__global__ __launch_bounds__(WVM * WVN * 64) void gemm_mfma(
    int N, PairT q0, PairT q1, PairT q2,
    const float* __restrict__ bias1, const float* __restrict__ bias2,
    OutT* __restrict__ Cc, long ldc)
{
    const int tid  = threadIdx.x;
    const int w    = tid >> 6;
    const int lane = tid & 63;
    const int lr   = lane & 15;
    const int lg   = lane >> 4;
    const int mb   = SWAPXY ? blockIdx.x : blockIdx.y;
    const int nb   = SWAPXY ? blockIdx.y : blockIdx.x;
    const int mrow = mb * (WVM * WTM * 16) + (w / WVN) * (WTM * 16);
    const int ncol = nb * (WVN * WTN * 16) + (w % WVN) * (WTN * 16);

    f32x4 acc[WTM][WTN];
#pragma unroll
    for (int i = 0; i < WTM; ++i)
#pragma unroll
        for (int j = 0; j < WTN; ++j) acc[i][j] = (f32x4){0.f, 0.f, 0.f, 0.f};

    const PairT qs[3] = {q0, q1, q2};
#pragma unroll
    for (int p = 0; p < NP; ++p) {
        const PairT pp = qs[p];
        const int nk = pp.K >> 5;
        const u16*   Ab = (const u16*)pp.Ap;
        const float* Af = (const float*)pp.Ap;
        size_t aoff[WTM];
#pragma unroll
        for (int mi = 0; mi < WTM; ++mi)
            aoff[mi] = (size_t)(mrow + mi * 16 + lr) * pp.lda + lg * 8;
        const u16* Bp = pp.Bt + (size_t)(ncol + lr) * pp.ldb + lg * 8;

#pragma unroll 2
        for (int kk = 0; kk < nk; ++kk) {
            const int ko = kk * 32;
            bf16x8 av[WTM], bv[WTN];
#pragma unroll
            for (int mi = 0; mi < WTM; ++mi) {
                if (AF32) av[mi] = cvt_bf8(Af + aoff[mi] + ko);
                else      av[mi] = ld_bf8(Ab + aoff[mi] + ko);
            }
#pragma unroll
            for (int ni = 0; ni < WTN; ++ni)
                bv[ni] = ld_bf8(Bp + ko + (size_t)(ni * 16) * pp.ldb);
#pragma unroll
            for (int mi = 0; mi < WTM; ++mi)
#pragma unroll
                for (int ni = 0; ni < WTN; ++ni)
                    acc[mi][ni] = __builtin_amdgcn_mfma_f32_16x16x32_bf16(
                        av[mi], bv[ni], acc[mi][ni], 0, 0, 0);
        }
    }

#pragma unroll
    for (int ni = 0; ni < WTN; ++ni) {
        const int col = ncol + ni * 16 + lr;
        if (col >= N) continue;
        float bs = 0.f;
        if (bias1) bs += bias1[col];
        if (bias2) bs += bias2[col];
#pragma unroll
        for (int mi = 0; mi < WTM; ++mi) {
#pragma unroll
            for (int r = 0; r < 4; ++r) {
                const int row = mrow + mi * 16 + lg * 4 + r;
                const float v = acc[mi][ni][r] + bs;
                if constexpr (sizeof(OutT) == 2)
                    Cc[(size_t)row * ldc + col] = (OutT)f2bf(v);
                else
                    Cc[(size_t)row * ldc + col] = v;
            }
        }
    }
}

// ===========================================================================
// Generic LDS-staged 128x128 GEMM (BK=64, 4 waves 2x2, XOR swizzle).
// grid = (M/128, N/128). Up to 2 fused pairs (K multiple of 64), 2 biases.
// ===========================================================================
template <int NP, typename OutT>
__global__ __launch_bounds__(256) void gemm_lds(
    int N, PairT q0, PairT q1,
    const float* __restrict__ bias1, const float* __restrict__ bias2,
    OutT* __restrict__ Cc, long ldc)
{
    __shared__ u16 As[128 * 64];
    __shared__ u16 Bs[128 * 64];

    const int tid  = threadIdx.x;
    const int w    = tid >> 6;
    const int lane = tid & 63;
    const int lr   = lane & 15;
    const int lg   = lane >> 4;
    const int brow = blockIdx.x * 128;
    const int bcol = blockIdx.y * 128;
    const int wrow = (w >> 1) * 64;
    const int wcol = (w & 1) * 64;

    int arow[4], acb[4], aphys[4];
#pragma unroll
    for (int i = 0; i < 4; ++i) {
        const int s = (tid + 256 * i) * 16;
        arow[i]  = s >> 7;
        acb[i]   = s & 127;
        aphys[i] = (s ^ ((arow[i] & 7) << 4)) >> 1;
    }

    int aoff[2][4], boff[2][4];
#pragma unroll
    for (int kh = 0; kh < 2; ++kh) {
#pragma unroll
        for (int i = 0; i < 4; ++i) {
            const int ra = wrow + i * 16 + lr;
            aoff[kh][i] = (((ra << 7) + (kh << 6) + (lg << 4)) ^ ((ra & 7) << 4)) >> 1;
            const int rb = wcol + i * 16 + lr;
            boff[kh][i] = (((rb << 7) + (kh << 6) + (lg << 4)) ^ ((rb & 7) << 4)) >> 1;
        }
    }

    f32x4 acc[4][4];
#pragma unroll
    for (int i = 0; i < 4; ++i)
#pragma unroll
        for (int j = 0; j < 4; ++j) acc[i][j] = (f32x4){0.f, 0.f, 0.f, 0.f};

    const PairT qs[2] = {q0, q1};
#pragma unroll
    for (int p = 0; p < NP; ++p) {
        const u16* Ab = (const u16*)qs[p].Ap;
        const u16* Bt = qs[p].Bt;
        const long lda = qs[p].lda;
        const long ldb = qs[p].ldb;
        const int  K   = qs[p].K;

        for (int k0 = 0; k0 < K; k0 += 64) {
            u16x8 av[4], bv[4];
#pragma unroll
            for (int i = 0; i < 4; ++i) {
                av[i] = *reinterpret_cast<const u16x8*>(
                    Ab + (size_t)(brow + arow[i]) * lda + k0 + (acb[i] >> 1));
                bv[i] = *reinterpret_cast<const u16x8*>(
                    Bt + (size_t)(bcol + arow[i]) * ldb + k0 + (acb[i] >> 1));
            }
            __syncthreads();
#pragma unroll
            for (int i = 0; i < 4; ++i) {
                *reinterpret_cast<u16x8*>(As + aphys[i]) = av[i];
                *reinterpret_cast<u16x8*>(Bs + aphys[i]) = bv[i];
            }
            __syncthreads();

#pragma unroll
            for (int kh = 0; kh < 2; ++kh) {
                bf16x8 af[4], bf_[4];
#pragma unroll
                for (int mi = 0; mi < 4; ++mi)
                    af[mi] = __builtin_bit_cast(bf16x8,
                        *reinterpret_cast<const u16x8*>(As + aoff[kh][mi]));
#pragma unroll
                for (int ni = 0; ni < 4; ++ni)
                    bf_[ni] = __builtin_bit_cast(bf16x8,
                        *reinterpret_cast<const u16x8*>(Bs + boff[kh][ni]));
#pragma unroll
                for (int mi = 0; mi < 4; ++mi)
#pragma unroll
                    for (int ni = 0; ni < 4; ++ni)
                        acc[mi][ni] = __builtin_amdgcn_mfma_f32_16x16x32_bf16(
                            af[mi], bf_[ni], acc[mi][ni], 0, 0, 0);
            }
        }
    }

#pragma unroll
    for (int ni = 0; ni < 4; ++ni) {
        const int col = bcol + wcol + ni * 16 + lr;
        if (col >= N) continue;
        float bs = 0.f;
        if (bias1) bs += bias1[col];
        if (bias2) bs += bias2[col];
#pragma unroll
        for (int mi = 0; mi < 4; ++mi) {
#pragma unroll
            for (int r = 0; r < 4; ++r) {
                const int row = brow + wrow + mi * 16 + lg * 4 + r;
                const float v = acc[mi][ni][r] + bs;
                if constexpr (sizeof(OutT) == 2)
                    Cc[(size_t)row * ldc + col] = (OutT)f2bf(v);
                else
                    Cc[(size_t)row * ldc + col] = v;
            }
        }
    }
}

// ===========================================================================
// enc_att v2: C[M][256] = A[M][2048] @ Bt[256][2048]^T + bias.
// ONE block per 128-M-tile covers full N=256: 8 waves (2M x 4N of 64x64),
// LDS A 128x64 (16KB) + B 256x64 (32KB), XOR swizzle. F read exactly once.
// grid = (M/128), 512 threads.
// ===========================================================================
__global__ __launch_bounds__(512) void gemm_enc2(
    const u16* __restrict__ Abf,   // [M][2048] bf16
    const u16* __restrict__ Bt,    // [256][2048] bf16
    const float* __restrict__ bias,
    u16* __restrict__ Cc)          // [M][256] bf16
{
    __shared__ u16 As[128 * 64];
    __shared__ u16 Bs[256 * 64];

    const int tid  = threadIdx.x;
    const int w    = tid >> 6;          // 0..7
    const int lane = tid & 63;
    const int lr   = lane & 15;
    const int lg   = lane >> 4;
    const int brow = blockIdx.x * 128;
    const int wrow = (w >> 2) * 64;     // 0 or 64
    const int wcol = (w & 3) * 64;      // 0,64,128,192

    // staging geometry: A chunks (2/thread), B chunks (4/thread)
    int arow[2], acb[2], aphys[2];
#pragma unroll
    for (int i = 0; i < 2; ++i) {
        const int s = (tid + 512 * i) * 16;      // 0..16384
        arow[i]  = s >> 7;
        acb[i]   = s & 127;
        aphys[i] = (s ^ ((arow[i] & 7) << 4)) >> 1;
    }
    int brow_s[4], bcb[4], bphys[4];
#pragma unroll
    for (int i = 0; i < 4; ++i) {
        const int s = (tid + 512 * i) * 16;      // 0..32768
        brow_s[i] = s >> 7;
        bcb[i]    = s & 127;
        bphys[i]  = (s ^ ((brow_s[i] & 7) << 4)) >> 1;
    }

    int aoff[2][4], boff[2][4];
#pragma unroll
    for (int kh = 0; kh < 2; ++kh) {
#pragma unroll
        for (int i = 0; i < 4; ++i) {
            const int ra = wrow + i * 16 + lr;   // < 128
            aoff[kh][i] = (((ra << 7) + (kh << 6) + (lg << 4)) ^ ((ra & 7) << 4)) >> 1;
            const int rb = wcol + i * 16 + lr;   // < 256
            boff[kh][i] = (((rb << 7) + (kh << 6) + (lg << 4)) ^ ((rb & 7) << 4)) >> 1;
        }
    }

    f32x4 acc[4][4];
#pragma unroll
    for (int i = 0; i < 4; ++i)
#pragma unroll
        for (int j = 0; j < 4; ++j) acc[i][j] = (f32x4){0.f, 0.f, 0.f, 0.f};

    for (int k0 = 0; k0 < 2048; k0 += 64) {
        u16x8 av[2], bv[4];
#pragma unroll
        for (int i = 0; i < 2; ++i)
            av[i] = *reinterpret_cast<const u16x8*>(
                Abf + (size_t)(brow + arow[i]) * 2048 + k0 + (acb[i] >> 1));
#pragma unroll
        for (int i = 0; i < 4; ++i)
            bv[i] = *reinterpret_cast<const u16x8*>(
                Bt + (size_t)brow_s[i] * 2048 + k0 + (bcb[i] >> 1));
        __syncthreads();
#pragma unroll
        for (int i = 0; i < 2; ++i)
            *reinterpret_cast<u16x8*>(As + aphys[i]) = av[i];
#pragma unroll
        for (int i = 0; i < 4; ++i)
            *reinterpret_cast<u16x8*>(Bs + bphys[i]) = bv[i];
        __syncthreads();

#pragma unroll
        for (int kh = 0; kh < 2; ++kh) {
            bf16x8 af[4], bf_[4];
#pragma unroll
            for (int mi = 0; mi < 4; ++mi)
                af[mi] = __builtin_bit_cast(bf16x8,
                    *reinterpret_cast<const u16x8*>(As + aoff[kh][mi]));
#pragma unroll
            for (int ni = 0; ni < 4; ++ni)
                bf_[ni] = __builtin_bit_cast(bf16x8,
                    *reinterpret_cast<const u16x8*>(Bs + boff[kh][ni]));
#pragma unroll
            for (int mi = 0; mi < 4; ++mi)
#pragma unroll
                for (int ni = 0; ni < 4; ++ni)
                    acc[mi][ni] = __builtin_amdgcn_mfma_f32_16x16x32_bf16(
                        af[mi], bf_[ni], acc[mi][ni], 0, 0, 0);
        }
    }

#pragma unroll
    for (int ni = 0; ni < 4; ++ni) {
        const int col = wcol + ni * 16 + lr;
        const float bs = bias[col];
#pragma unroll
        for (int mi = 0; mi < 4; ++mi) {
#pragma unroll
            for (int r = 0; r < 4; ++r) {
                const int row = brow + wrow + mi * 16 + lg * 4 + r;
                Cc[(size_t)row * 256 + col] = f2bf(acc[mi][ni][r] + bs);
            }
        }
    }
}

// ===========================================================================
// init xin h-section = h0 (gates kernel reads it at t=0)
// ===========================================================================
__global__ __launch_bounds__(256) void init_xin_h(
    const u16* __restrict__ h_cur, u16* __restrict__ xin)
{
    const int idx = blockIdx.x * 256 + threadIdx.x;  // B*D
    const int b = idx >> 9;
    const int d = idx & (D - 1);
    xin[(size_t)b * KCAT + 2048 + d] = h_cur[idx];
}

// ===========================================================================
// K1: fused [LSTM-finish(t-1)] + dec_att + scores + softmax + context(t).
// grid = 256 blocks (pair per batch row), 256 threads.
// ===========================================================================
template <bool FBF>
__global__ __launch_bounds__(256) void alpha_ctx_lstm(
    const void* __restrict__ Fv,        // F_bf (u16) or F (float)
    const u16*  __restrict__ enc,       // [B*S][A]
    const u16*  __restrict__ W_daT,     // [A][D]
    const float* __restrict__ b_da,
    const float* __restrict__ W_fa,
    const float* __restrict__ b_ih_,
    const float* __restrict__ b_hh_,
    const float* __restrict__ egates,   // [B*T][2048] fp32 (interleaved cols)
    const float* __restrict__ part,     // [4][B][2048] split-K partials
    const float* __restrict__ c_rd,
    float* __restrict__ c_wr,
    const u16*  __restrict__ h0,        // initial h (used at t==0)
    u16* __restrict__ h_all,            // [B*T][D]
    u16* __restrict__ ctx_all,          // [B*T][E]
    u16* __restrict__ xin,              // [B][KCAT]
    int t)
{
    const int blk  = blockIdx.x;
    const int tid  = threadIdx.x;
    const int w    = tid >> 6;
    const int lane = tid & 63;
    const int b    = blk >> 1;
    const int q    = blk & 1;

    __shared__ float hl[D];
    __shared__ float dec[A];
    __shared__ float wfa[A];
    __shared__ float sc[S];
    __shared__ float red[8];

    if (t == 0) {
        hl[tid]       = bf2f(h0[b * D + tid]);
        hl[tid + 256] = bf2f(h0[b * D + 256 + tid]);
    } else {
        const int tt = t - 1;
#pragma unroll
        for (int half = 0; half < 2; ++half) {
            const int d = tid + half * 256;
            float g4[4];
#pragma unroll
            for (int g = 0; g < 4; ++g) {
                const int col = ((d >> 4) << 6) + (g << 4) + (d & 15);
                float s = b_ih_[g * D + d] + b_hh_[g * D + d] +
                          egates[((size_t)(b * T + tt) << 11) + col];
#pragma unroll
                for (int z = 0; z < 4; ++z)
                    s += part[((size_t)(z * B + b) << 11) + col];
                g4[g] = s;
            }
            const int idx = (b << 9) + d;
            const float cn = sigm(g4[1]) * c_rd[idx] + sigm(g4[0]) * tanhf(g4[2]);
            const float hf = sigm(g4[3]) * tanhf(cn);
            hl[d] = hf;
            if (q == 0) {
                c_wr[idx] = cn;
                const u16 hv = f2bf(hf);
                h_all[((size_t)(b * T + tt)) * D + d] = hv;
                xin[(size_t)b * KCAT + 2048 + d] = hv;
            }
        }
    }
    wfa[tid] = W_fa[tid];
    __syncthreads();

    // dec[a] = h . W_da[:,a] + b_da[a]  (redundant across the pair)
    {
        float acc = 0.f;
        const u16* wr = W_daT + (size_t)tid * D;
#pragma unroll 4
        for (int i = 0; i < D / 8; ++i) {
            const u16x8 v = *reinterpret_cast<const u16x8*>(wr + i * 8);
#pragma unroll
            for (int j = 0; j < 8; ++j) acc += bf2f(v[j]) * hl[i * 8 + j];
        }
        dec[tid] = acc + b_da[tid];
    }
    __syncthreads();

    // scores (b_fa dropped: softmax shift-invariant)
    if (tid < S) {
        const u16* er = enc + ((size_t)b * S + tid) * A;
        float v = 0.f;
#pragma unroll 4
        for (int i = 0; i < A / 8; ++i) {
            const u16x8 e8 = *reinterpret_cast<const u16x8*>(er + i * 8);
#pragma unroll
            for (int j = 0; j < 8; ++j) {
                float x = bf2f(e8[j]) + dec[i * 8 + j];
                x = x > 0.f ? x : 0.f;
                v += x * wfa[i * 8 + j];
            }
        }
        sc[tid] = v;
    }
    __syncthreads();

    float m = -1e30f;
    for (int s = tid; s < S; s += 256) m = fmaxf(m, sc[s]);
    for (int off = 32; off; off >>= 1) m = fmaxf(m, __shfl_down(m, off));
    if (lane == 0) red[w] = m;
    __syncthreads();
    if (tid == 0) red[0] = fmaxf(fmaxf(red[0], red[1]), fmaxf(red[2], red[3]));
    __syncthreads();
    m = red[0];

    float sum = 0.f;
    for (int s = tid; s < S; s += 256) {
        const float ev = __expf(sc[s] - m);
        sc[s] = ev;
        sum += ev;
    }
    for (int off = 32; off; off >>= 1) sum += __shfl_down(sum, off);
    if (lane == 0) red[4 + w] = sum;
    __syncthreads();
    if (tid == 0) red[4] = red[4] + red[5] + red[6] + red[7];
    __syncthreads();
    const float inv = 1.f / red[4];

    // context: e = q*1024 + tid*4 ; 4 s-streams of 49 (28 loads in flight)
    {
        const int e0 = q * 1024 + tid * 4;
        float a0 = 0.f, a1 = 0.f, a2 = 0.f, a3 = 0.f;
        float b0 = 0.f, b1 = 0.f, b2 = 0.f, b3 = 0.f;
        float c0 = 0.f, c1 = 0.f, c2 = 0.f, c3 = 0.f;
        float d0 = 0.f, d1 = 0.f, d2 = 0.f, d3 = 0.f;
        if (FBF) {
            const u16* F0 = (const u16*)Fv + (size_t)b * S * E + e0;
            const u16* F1 = F0 + (size_t)49 * E;
            const u16* F2 = F0 + (size_t)98 * E;
            const u16* F3 = F0 + (size_t)147 * E;
#pragma unroll 7
            for (int s = 0; s < 49; ++s) {
                const u16x4 v0 = *reinterpret_cast<const u16x4*>(F0 + (size_t)s * E);
                const u16x4 v1 = *reinterpret_cast<const u16x4*>(F1 + (size_t)s * E);
                const u16x4 v2 = *reinterpret_cast<const u16x4*>(F2 + (size_t)s * E);
                const u16x4 v3 = *reinterpret_cast<const u16x4*>(F3 + (size_t)s * E);
                const float l0 = sc[s], l1 = sc[s + 49], l2 = sc[s + 98], l3 = sc[s + 147];
                a0 += l0 * bf2f(v0[0]); a1 += l0 * bf2f(v0[1]);
                a2 += l0 * bf2f(v0[2]); a3 += l0 * bf2f(v0[3]);
                b0 += l1 * bf2f(v1[0]); b1 += l1 * bf2f(v1[1]);
                b2 += l1 * bf2f(v1[2]); b3 += l1 * bf2f(v1[3]);
                c0 += l2 * bf2f(v2[0]); c1 += l2 * bf2f(v2[1]);
                c2 += l2 * bf2f(v2[2]); c3 += l2 * bf2f(v2[3]);
                d0 += l3 * bf2f(v3[0]); d1 += l3 * bf2f(v3[1]);
                d2 += l3 * bf2f(v3[2]); d3 += l3 * bf2f(v3[3]);
            }
        } else {
            const float* F0 = (const float*)Fv + (size_t)b * S * E + e0;
            const float* F1 = F0 + (size_t)49 * E;
            const float* F2 = F0 + (size_t)98 * E;
            const float* F3 = F0 + (size_t)147 * E;
#pragma unroll 7
            for (int s = 0; s < 49; ++s) {
                const float4 v0 = *reinterpret_cast<const float4*>(F0 + (size_t)s * E);
                const float4 v1 = *reinterpret_cast<const float4*>(F1 + (size_t)s * E);
                const float4 v2 = *reinterpret_cast<const float4*>(F2 + (size_t)s * E);
                const float4 v3 = *reinterpret_cast<const float4*>(F3 + (size_t)s * E);
                const float l0 = sc[s], l1 = sc[s + 49], l2 = sc[s + 98], l3 = sc[s + 147];
                a0 += l0 * v0.x; a1 += l0 * v0.y; a2 += l0 * v0.z; a3 += l0 * v0.w;
                b0 += l1 * v1.x; b1 += l1 * v1.y; b2 += l1 * v1.z; b3 += l1 * v1.w;
                c0 += l2 * v2.x; c1 += l2 * v2.y; c2 += l2 * v2.z; c3 += l2 * v2.w;
                d0 += l3 * v3.x; d1 += l3 * v3.y; d2 += l3 * v3.z; d3 += l3 * v3.w;
            }
        }
        a0 += b0 + c0 + d0; a1 += b1 + c1 + d1;
        a2 += b2 + c2 + d2; a3 += b3 + c3 + d3;
        u16x4 o;
        o[0] = f2bf(a0 * inv); o[1] = f2bf(a1 * inv);
        o[2] = f2bf(a2 * inv); o[3] = f2bf(a3 * inv);
        *reinterpret_cast<u16x4*>(ctx_all + ((size_t)(b * T + t)) * E + e0) = o;
        *reinterpret_cast<u16x4*>(xin + (size_t)b * KCAT + e0) = o;
    }
}

// ===========================================================================
// K2: gates split-K4 over xin=[ctx;h] (KCAT=2560, 4 chunks of 640) vs W_chT.
// Wave tile 16M x 64N, 2 waves/block. grid = (16, 8, 4), 128 threads.
// ===========================================================================
__global__ __launch_bounds__(128) void gates_split4(
    const u16* __restrict__ xin, const u16* __restrict__ W_chT,
    float* __restrict__ part)
{
    const int tid  = threadIdx.x;
    const int w    = tid >> 6;
    const int lane = tid & 63;
    const int lr   = lane & 15;
    const int lg   = lane >> 4;
    const int mrow = blockIdx.y * 16;
    const int ncol = blockIdx.x * 128 + w * 64;
    const int z    = blockIdx.z;
    const int kb   = z * 640;

    f32x4 acc[4];
#pragma unroll
    for (int j = 0; j < 4; ++j) acc[j] = (f32x4){0.f, 0.f, 0.f, 0.f};

    const u16* Ap = xin + (size_t)(mrow + lr) * KCAT + kb + lg * 8;
    const u16* Bp = W_chT + (size_t)(ncol + lr) * KCAT + kb + lg * 8;

#pragma unroll 4
    for (int kk = 0; kk < 20; ++kk) {
        const int ko = kk * 32;
        const bf16x8 av = ld_bf8(Ap + ko);
        bf16x8 bv[4];
#pragma unroll
        for (int ni = 0; ni < 4; ++ni)
            bv[ni] = ld_bf8(Bp + ko + (size_t)(ni * 16) * KCAT);
#pragma unroll
        for (int ni = 0; ni < 4; ++ni)
            acc[ni] = __builtin_amdgcn_mfma_f32_16x16x32_bf16(av, bv[ni], acc[ni], 0, 0, 0);
    }

#pragma unroll
    for (int ni = 0; ni < 4; ++ni) {
        const int col = ncol + ni * 16 + lr;
#pragma unroll
        for (int r = 0; r < 4; ++r) {
            const int row = mrow + lg * 4 + r;
            part[((size_t)(z * B + row) << 11) + col] = acc[ni][r];
        }
    }
}

// ===========================================================================
// lstm_last: LSTM finish for t = T-1 (only h_all needed). grid = 256.
// ===========================================================================
__global__ __launch_bounds__(256) void lstm_last(
    const float* __restrict__ part,
    const float* __restrict__ egates,
    const float* __restrict__ b_ih_, const float* __restrict__ b_hh_,
    const float* __restrict__ c_rd,
    u16* __restrict__ h_all)
{
    const int idx = blockIdx.x * 256 + threadIdx.x;  // B*D
    const int b = idx >> 9;
    const int d = idx & (D - 1);
    const int tt = T - 1;
    float g4[4];
#pragma unroll
    for (int g = 0; g < 4; ++g) {
        const int col = ((d >> 4) << 6) + (g << 4) + (d & 15);
        float s = b_ih_[g * D + d] + b_hh_[g * D + d] +
                  egates[((size_t)(b * T + tt) << 11) + col];
#pragma unroll
        for (int z = 0; z < 4; ++z)
            s += part[((size_t)(z * B + b) << 11) + col];
        g4[g] = s;
    }
    const float cn = sigm(g4[1]) * c_rd[idx] + sigm(g4[0]) * tanhf(g4[2]);
    h_all[((size_t)(b * T + tt)) * D + d] = f2bf(sigm(g4[3]) * tanhf(cn));
}

// ===========================================================================
// Fused weight transposes: one launch, segment table.
// ===========================================================================
struct TSeg {
    const float* src; u16* dst;
    int K; int N; int ldo; int ko; int mode; int tilesX; int nblk;
};
struct TransArgs { TSeg seg[10]; };

__global__ __launch_bounds__(256) void transpose_all(TransArgs a)
{
    __shared__ float tls[32][33];
    int bid = blockIdx.x;
    int si = 0;
    while (si < 9 && bid >= a.seg[si].nblk) { bid -= a.seg[si].nblk; ++si; }
    const TSeg s = a.seg[si];
    const int n0 = (bid % s.tilesX) * 32;
    const int k0 = (bid / s.tilesX) * 32;
    const int c  = threadIdx.x & 31;
    const int r8 = threadIdx.x >> 5;

#pragma unroll
    for (int i = 0; i < 4; ++i) {
        const int k = r8 + i * 8;
        float v = 0.f;
        if (n0 + c < s.N) v = s.src[(size_t)(k0 + k) * s.N + n0 + c];
        tls[k][c] = v;
    }
    __syncthreads();
#pragma unroll
    for (int i = 0; i < 4; ++i) {
        const int nn = r8 + i * 8;
        const int n = n0 + nn;
        int row;
        if (s.mode) {
            const int g = n >> 9, d = n & (D - 1);
            row = ((d >> 4) << 6) + (g << 4) + (d & 15);
        } else {
            row = n;
        }
        s.dst[(size_t)row * s.ldo + s.ko + k0 + c] = f2bf(tls[c][nn]);
    }
}

// ===========================================================================
// fused: mean over S (fp32 acc -> bf16) and optional F -> bf16 copy
// ===========================================================================
template <bool WRITE>
__global__ __launch_bounds__(256) void conv_mean(
    const float* __restrict__ F, u16* __restrict__ Fbf, u16* __restrict__ meanbf)
{
    const int idx = blockIdx.x * 256 + threadIdx.x;  // over B*E
    const int b = idx >> 11;
    const int e = idx & (E - 1);
    const float* src = F + (size_t)b * S * E + e;
    float acc = 0.f;
#pragma unroll 8
    for (int s = 0; s < S; ++s) {
        const float v = src[(size_t)s * E];
        acc += v;
        if (WRITE) Fbf[(size_t)b * S * E + (size_t)s * E + e] = f2bf(v);
    }
    meanbf[idx] = f2bf(acc * (1.f / (float)S));
}

// ===========================================================================
// embedding gather -> bf16 embs [B][T][EM]
// ===========================================================================
__global__ __launch_bounds__(256) void gather_embs_bf(
    const int* __restrict__ captions, const float* __restrict__ table,
    u16* __restrict__ out)
{
    const int idx = blockIdx.x * 256 + threadIdx.x;  // B*T*(EM/8)
    const int row = idx >> 6;
    const int ch  = idx & 63;
    const int cap = captions[row];
    const float* src = table + (size_t)cap * EM + ch * 8;
    float4 u = *reinterpret_cast<const float4*>(src);
    float4 v = *reinterpret_cast<const float4*>(src + 4);
    u16x8 t;
    t[0] = f2bf(u.x); t[1] = f2bf(u.y); t[2] = f2bf(u.z); t[3] = f2bf(u.w);
    t[4] = f2bf(v.x); t[5] = f2bf(v.y); t[6] = f2bf(v.z); t[7] = f2bf(v.w);
    *reinterpret_cast<u16x8*>(out + (size_t)row * EM + ch * 8) = t;
}

// ===========================================================================
// ======================= fp32 fallback path ================================
// ===========================================================================
struct Pair {
    const float* Aptr; int lda; const float* Wptr; int ldw; int K;
};

template <int NP>
__global__ __launch_bounds__(256) void gemm_f32(
    int M, int N, Pair p0, Pair p1, Pair p2,
    const float* __restrict__ bias1, const float* __restrict__ bias2,
    float* __restrict__ C, long ldc)
{
    __shared__ float As[64][17];
    __shared__ float Ws[16][64];
    const int tid = threadIdx.x;
    const int row0 = blockIdx.y * 64, col0 = blockIdx.x * 64;
    const int tx = tid & 15, ty = tid >> 4;
    float acc[4][4] = {};
    Pair ps[3] = {p0, p1, p2};
#pragma unroll
    for (int p = 0; p < NP; ++p) {
        const float* Ag = ps[p].Aptr; const float* Wg = ps[p].Wptr;
        const int lda = ps[p].lda, ldw = ps[p].ldw, K = ps[p].K;
        for (int k0 = 0; k0 < K; k0 += 16) {
            {
                const int k = tid & 15, mb = tid >> 4;
#pragma unroll
                for (int i = 0; i < 4; ++i) {
                    const int m = mb + 16 * i, gr = row0 + m;
                    float v = 0.f;
                    if (gr < M) v = Ag[(size_t)gr * lda + k0 + k];
                    As[m][k] = v;
                }
            }
            {
                const int n = tid & 63, kb = tid >> 6, gc = col0 + n;
#pragma unroll
                for (int i = 0; i < 4; ++i) {
                    const int k = kb * 4 + i;
                    float v = 0.f;
                    if (gc < N) v = Wg[(size_t)(k0 + k) * ldw + gc];
                    Ws[k][n] = v;
                }
            }
            __syncthreads();
#pragma unroll
            for (int k = 0; k < 16; ++k) {
                float av[4];
#pragma unroll
                for (int i = 0; i < 4; ++i) av[i] = As[ty * 4 + i][k];
                const float4 bv = reinterpret_cast<const float4*>(&Ws[k][0])[tx];
                const float bvv[4] = {bv.x, bv.y, bv.z, bv.w};
#pragma unroll
                for (int i = 0; i < 4; ++i)
#pragma unroll
                    for (int j = 0; j < 4; ++j) acc[i][j] += av[i] * bvv[j];
            }
            __syncthreads();
        }
    }
#pragma unroll
    for (int i = 0; i < 4; ++i) {
        const int r = row0 + ty * 4 + i;
        if (r >= M) continue;
#pragma unroll
        for (int j = 0; j < 4; ++j) {
            const int cidx = col0 + tx * 4 + j;
            if (cidx >= N) continue;
            float v = acc[i][j];
            if (bias1) v += bias1[cidx];
            if (bias2) v += bias2[cidx];
            C[(size_t)r * ldc + cidx] = v;
        }
    }
}

__global__ __launch_bounds__(256) void mean_pool(const float* __restrict__ F,
                                                 float* __restrict__ mean)
{
    const int idx = blockIdx.x * 256 + threadIdx.x;
    const int b = idx >> 11, e = idx & (E - 1);
    const float* Fb = F + (size_t)b * S * E + e;
    float acc = 0.f;
    for (int s = 0; s < S; ++s) acc += Fb[(size_t)s * E];
    mean[idx] = acc * (1.f / (float)S);
}

__global__ __launch_bounds__(256) void gather_embs(const int* __restrict__ captions,
                                                   const float* __restrict__ table,
                                                   float* __restrict__ out)
{
    const int idx = blockIdx.x * 256 + threadIdx.x;
    const int per_row = EM / 4;
    const int row = idx / per_row;
    const int col = idx - row * per_row;
    const int cap = captions[row];
    reinterpret_cast<float4*>(out)[idx] =
        reinterpret_cast<const float4*>(table + (size_t)cap * EM)[col];
}

__global__ __launch_bounds__(256) void attn_softmax(
    const float* __restrict__ enc_att, const float* __restrict__ dec_att,
    const float* __restrict__ W_fa, const float* __restrict__ b_fa,
    float* __restrict__ alpha)
{
    const int b = blockIdx.x, tid = threadIdx.x;
    const int wave = tid >> 6, lane = tid & 63;
    __shared__ float dec[A], wfa[A], sc[S], redm[4], reds[4];
    dec[tid] = dec_att[b * A + tid];
    wfa[tid] = W_fa[tid];
    __syncthreads();
    for (int s = wave; s < S; s += 4) {
        const float* ea = enc_att + ((size_t)b * S + s) * A;
        float v = 0.f;
#pragma unroll
        for (int i = 0; i < 4; ++i) {
            const int a = lane + 64 * i;
            float x = ea[a] + dec[a];
            x = x > 0.f ? x : 0.f;
            v += x * wfa[a];
        }
        for (int off = 32; off; off >>= 1) v += __shfl_down(v, off);
        if (lane == 0) sc[s] = v + b_fa[0];
    }
    __syncthreads();
    float m = -1e30f;
    for (int s = tid; s < S; s += 256) m = fmaxf(m, sc[s]);
    for (int off = 32; off; off >>= 1) m = fmaxf(m, __shfl_down(m, off));
    if (lane == 0) redm[wave] = m;
    __syncthreads();
    if (tid == 0) redm[0] = fmaxf(fmaxf(redm[0], redm[1]), fmaxf(redm[2], redm[3]));
    __syncthreads();
    m = redm[0];
    float sum = 0.f;
    for (int s = tid; s < S; s += 256) {
        const float ev = expf(sc[s] - m);
        sc[s] = ev; sum += ev;
    }
    for (int off = 32; off; off >>= 1) sum += __shfl_down(sum, off);
    if (lane == 0) reds[wave] = sum;
    __syncthreads();
    if (tid == 0) reds[0] = reds[0] + reds[1] + reds[2] + reds[3];
    __syncthreads();
    const float inv = 1.f / reds[0];
    for (int s = tid; s < S; s += 256) alpha[b * S + s] = sc[s] * inv;
}

__global__ __launch_bounds__(256) void context_kernel(
    const float* __restrict__ F, const float* __restrict__ alpha,
    float* __restrict__ ctx)
{
    const int chunks = E / 256;
    const int b = blockIdx.x / chunks;
    const int ec = blockIdx.x - b * chunks;
    const int e = ec * 256 + threadIdx.x;
    __shared__ float al[S];
    for (int s = threadIdx.x; s < S; s += 256) al[s] = alpha[b * S + s];
    __syncthreads();
    const float* Fb = F + (size_t)b * S * E + e;
    float acc = 0.f;
    for (int s = 0; s < S; ++s) acc += al[s] * Fb[(size_t)s * E];
    ctx[b * E + e] = acc;
}

__global__ __launch_bounds__(256) void lstm_cell(
    const float* __restrict__ gates, float* __restrict__ h, float* __restrict__ c)
{
    const int idx = blockIdx.x * 256 + threadIdx.x;
    const int b = idx >> 9, d = idx & (D - 1);
    const float* g = gates + (size_t)b * 4 * D;
    const float gi = g[d], gf = g[D + d], gg = g[2 * D + d], go = g[3 * D + d];
    const float cn = sigm(gf) * c[idx] + sigm(gi) * tanhf(gg);
    c[idx] = cn;
    h[idx] = sigm(go) * tanhf(cn);
}

// ===========================================================================
// launch
// ===========================================================================
extern "C" void kernel_launch(void* const* d_in, const int* in_sizes, int n_in,
                              void* d_out, int out_size, void* d_ws, size_t ws_size,
                              hipStream_t stream)
{
    const float* F        = (const float*)d_in[0];
    const int*   captions = (const int*)  d_in[1];
    const float* table    = (const float*)d_in[2];
    const float* W_ea     = (const float*)d_in[3];
    const float* b_ea     = (const float*)d_in[4];
    const float* W_da     = (const float*)d_in[5];
    const float* b_da     = (const float*)d_in[6];
    const float* W_fa     = (const float*)d_in[7];
    const float* b_fa     = (const float*)d_in[8];
    const float* W_ih     = (const float*)d_in[9];
    const float* b_ih     = (const float*)d_in[10];
    const float* W_hh     = (const float*)d_in[11];
    const float* b_hh     = (const float*)d_in[12];
    const float* W_cp     = (const float*)d_in[13];
    const float* b_cp     = (const float*)d_in[14];
    const float* W_hp     = (const float*)d_in[15];
    const float* b_hp     = (const float*)d_in[16];
    const float* W_op     = (const float*)d_in[17];
    const float* b_op     = (const float*)d_in[18];
    const float* W_inith  = (const float*)d_in[19];
    const float* b_inith  = (const float*)d_in[20];
    const float* W_initc  = (const float*)d_in[21];
    const float* b_initc  = (const float*)d_in[22];

    float* out = (float*)d_out;
    const int VP2 = 10240;  // V padded to 128-span

    // ---- workspace allocator (256 B aligned) ----
    char* base = (char*)d_ws;
    size_t off = 0;
    auto alloc = [&](size_t bytes) -> void* {
        off = (off + 255) & ~(size_t)255;
        void* p = base + off;
        off += bytes;
        return p;
    };

    u16* W_eaT    = (u16*)alloc((size_t)A * E * 2);
    u16* W_daT    = (u16*)alloc((size_t)A * D * 2);
    u16* W_iheT   = (u16*)alloc((size_t)2048 * EM * 2);     // emb section, interleaved
    u16* W_chT    = (u16*)alloc((size_t)2048 * KCAT * 2);   // [ctx;h] section, interleaved
    u16* W_cpT    = (u16*)alloc((size_t)EM * E * 2);
    u16* W_hpT    = (u16*)alloc((size_t)EM * D * 2);
    u16* W_opT    = (u16*)alloc((size_t)VP2 * EM * 2);
    u16* W_inithT = (u16*)alloc((size_t)D * E * 2);
    u16* W_initcT = (u16*)alloc((size_t)D * E * 2);
    u16* embs     = (u16*)alloc((size_t)B * T * EM * 2);
    u16* mean_bf  = (u16*)alloc((size_t)B * E * 2);
    u16* h_cur    = (u16*)alloc((size_t)B * D * 2);         // h0
    u16* h_all    = (u16*)alloc((size_t)B * T * D * 2);
    u16* ctx_all  = (u16*)alloc((size_t)B * T * E * 2);
    u16* xin      = (u16*)alloc((size_t)B * KCAT * 2);
    u16* feat_all = (u16*)alloc((size_t)B * T * EM * 2);
    u16* enc_bf   = (u16*)alloc((size_t)B * S * A * 2);
    float* cbuf0  = (float*)alloc((size_t)B * D * 4);
    float* cbuf1  = (float*)alloc((size_t)B * D * 4);
    float* egates = (float*)alloc((size_t)B * T * 2048 * 4);
    float* part   = (float*)alloc((size_t)4 * B * 2048 * 4);
    const size_t need_base = off;
    u16* F_bf     = (u16*)alloc((size_t)B * S * E * 2);
    const size_t need_fbf = off;

    const bool ok_base = need_base <= ws_size;
    const bool ok_fbf  = need_fbf <= ws_size;

    if (!ok_base) {
        // ---------------- fp32 fallback ----------------
        float* ws = (float*)d_ws;
        float* mean_feat = ws;  ws += B * E;
        float* h         = ws;  ws += B * D;
        float* c         = ws;  ws += B * D;
        float* enc_att   = ws;  ws += (size_t)B * S * A;
        float* fembs     = ws;  ws += (size_t)B * T * EM;
        float* fdec      = ws;  ws += B * A;
        float* falpha    = ws;  ws += B * S;
        float* fctx      = ws;  ws += B * E;
        float* fgates    = ws;  ws += B * 4 * D;
        float* ffeat     = ws;  ws += B * EM;
        const Pair ZP = {nullptr, 0, nullptr, 0, 0};
        mean_pool<<<(B * E) / 256, 256, 0, stream>>>(F, mean_feat);
        { Pair p = {mean_feat, E, W_inith, D, E};
          gemm_f32<1><<<dim3(D / 64, B / 64), 256, 0, stream>>>(B, D, p, ZP, ZP, b_inith, nullptr, h, D); }
        { Pair p = {mean_feat, E, W_initc, D, E};
          gemm_f32<1><<<dim3(D / 64, B / 64), 256, 0, stream>>>(B, D, p, ZP, ZP, b_initc, nullptr, c, D); }
        { Pair p = {F, E, W_ea, A, E};
          gemm_f32<1><<<dim3(A / 64, (B * S) / 64), 256, 0, stream>>>(B * S, A, p, ZP, ZP, b_ea, nullptr, enc_att, A); }
        gather_embs<<<(B * T * (EM / 4)) / 256, 256, 0, stream>>>(captions, table, fembs);
        for (int t = 0; t < T; ++t) {
            { Pair p = {h, D, W_da, A, D};
              gemm_f32<1><<<dim3(A / 64, B / 64), 256, 0, stream>>>(B, A, p, ZP, ZP, b_da, nullptr, fdec, A); }
            attn_softmax<<<B, 256, 0, stream>>>(enc_att, fdec, W_fa, b_fa, falpha);
            context_kernel<<<B * (E / 256), 256, 0, stream>>>(F, falpha, fctx);
            { Pair p0 = {fembs + (size_t)t * EM, T * EM, W_ih, 4 * D, EM};
              Pair p1 = {fctx, E, W_ih + (size_t)EM * 4 * D, 4 * D, E};
              Pair p2 = {h, D, W_hh, 4 * D, D};
              gemm_f32<3><<<dim3((4 * D) / 64, B / 64), 256, 0, stream>>>(B, 4 * D, p0, p1, p2, b_ih, b_hh, fgates, 4 * D); }
            lstm_cell<<<(B * D) / 256, 256, 0, stream>>>(fgates, h, c);
            { Pair p0 = {fctx, E, W_cp, EM, E};
              Pair p1 = {h, D, W_hp, EM, D};
              gemm_f32<2><<<dim3(EM / 64, B / 64), 256, 0, stream>>>(B, EM, p0, p1, ZP, b_cp, b_hp, ffeat, EM); }
            { Pair p = {ffeat, EM, W_op, V, EM};
              gemm_f32<1><<<dim3((V + 63) / 64, B / 64), 256, 0, stream>>>(B, V, p, ZP, ZP, b_op, nullptr, out + (size_t)t * V, (long)T * V); }
        }
        return;
    }

    // ---------------- bf16 MFMA path ----------------
    const PairT ZP = {nullptr, 0, nullptr, 0, 0};

    // fused weight transposes: one launch
    {
        TransArgs ta;
        auto seg = [&](int i, const float* src, u16* dst, int K, int N,
                       int ldo, int ko, int mode, int tilesX) {
            ta.seg[i] = {src, dst, K, N, ldo, ko, mode, tilesX, tilesX * (K / 32)};
        };
        seg(0, W_ea,    W_eaT,    2048, 256,   2048, 0,    0, 8);
        seg(1, W_da,    W_daT,    512,  256,   512,  0,    0, 8);
        seg(2, W_ih,    W_iheT,   512,  2048,  512,  0,    1, 64);
        seg(3, W_ih + (size_t)EM * 2048, W_chT, 2048, 2048, KCAT, 0, 1, 64);
        seg(4, W_hh,    W_chT,    512,  2048,  KCAT, 2048, 1, 64);
        seg(5, W_cp,    W_cpT,    2048, 512,   2048, 0,    0, 16);
        seg(6, W_hp,    W_hpT,    512,  512,   512,  0,    0, 16);
        seg(7, W_op,    W_opT,    512,  10000, 512,  0,    0, 320);
        seg(8, W_inith, W_inithT, 2048, 512,   2048, 0,    0, 16);
        seg(9, W_initc, W_initcT, 2048, 512,   2048, 0,    0, 16);
        int tot = 0;
        for (int i = 0; i < 10; ++i) tot += ta.seg[i].nblk;
        transpose_all<<<tot, 256, 0, stream>>>(ta);
    }

    if (ok_fbf)
        conv_mean<true><<<(B * E) / 256, 256, 0, stream>>>(F, F_bf, mean_bf);
    else
        conv_mean<false><<<(B * E) / 256, 256, 0, stream>>>(F, nullptr, mean_bf);

    gather_embs_bf<<<(B * T * (EM / 8)) / 256, 256, 0, stream>>>(captions, table, embs);

    // h0 (bf16), c0 (fp32 -> cbuf1: LSTM(0) reads cbuf1)
    { PairT p = {mean_bf, E, W_inithT, E, E};
      gemm_mfma<1, false, u16, 2, 4, 1, 4><<<dim3(2, 4), 256, 0, stream>>>(
          D, p, ZP, ZP, b_inith, nullptr, h_cur, D); }
    { PairT p = {mean_bf, E, W_initcT, E, E};
      gemm_mfma<1, false, float, 2, 4, 1, 4><<<dim3(2, 4), 256, 0, stream>>>(
          D, p, ZP, ZP, b_initc, nullptr, cbuf1, D); }

    // initialize xin h-section with h0
    init_xin_h<<<(B * D) / 256, 256, 0, stream>>>(h_cur, xin);

    // enc_att
    if (ok_fbf) {
        // v2: one block per M-tile covers full N=256; F read once
        gemm_enc2<<<dim3((B * S) / 128), 512, 0, stream>>>(F_bf, W_eaT, b_ea, enc_bf);
    } else {
        PairT p = {F, E, W_eaT, E, E};
        gemm_mfma<1, true, u16, 4, 4, 1, 4><<<dim3(1, (B * S) / 64), 256, 0, stream>>>(
            A, p, ZP, ZP, b_ea, nullptr, enc_bf, A);
    }

    // egates = emb @ W_ih[emb rows]: M=2560, N=2048, K=512 (LDS tiled)
    { PairT p = {embs, EM, W_iheT, EM, EM};
      gemm_lds<1, float><<<dim3(20, 16), 256, 0, stream>>>(
          2048, p, ZP, nullptr, nullptr, egates, 2048); }

    // ---- per-step loop: 2 kernels/step ----
    for (int t = 0; t < T; ++t) {
        const int tt = t - 1;  // LSTM step computed inside K1 (t>0)
        const float* crd = (tt >= 0 && (tt & 1)) ? cbuf0 : cbuf1;
        float*       cwr = (tt >= 0 && (tt & 1)) ? cbuf1 : cbuf0;

        if (ok_fbf)
            alpha_ctx_lstm<true><<<256, 256, 0, stream>>>(
                F_bf, enc_bf, W_daT, b_da, W_fa, b_ih, b_hh, egates, part,
                crd, cwr, h_cur, h_all, ctx_all, xin, t);
        else
            alpha_ctx_lstm<false><<<256, 256, 0, stream>>>(
                F, enc_bf, W_daT, b_da, W_fa, b_ih, b_hh, egates, part,
                crd, cwr, h_cur, h_all, ctx_all, xin, t);

        gates_split4<<<dim3(16, 8, 4), 128, 0, stream>>>(xin, W_chT, part);
    }

    // final LSTM (t = T-1): T-1=19 odd -> reads cbuf0
    lstm_last<<<(B * D) / 256, 256, 0, stream>>>(
        part, egates, b_ih, b_hh, ((T - 1) & 1) ? cbuf0 : cbuf1, h_all);

    // ---- batched tail: feat for all (b,t), then logits ----
    // feat: M=2560, N=512 (streaming; small panels)
    { PairT p0 = {ctx_all, E, W_cpT, E, E};
      PairT p1 = {h_all, D, W_hpT, D, D};
      gemm_mfma<2, false, u16, 1, 4, 2, 2, true><<<dim3((B * T) / 32, EM / 128), 256, 0, stream>>>(
          EM, p0, p1, ZP, b_cp, b_hp, feat_all, EM); }

    // logits: M=2560, N=10240(pad), K=512 (LDS tiled; x=M fast so W_opT panel L2-hot)
    { PairT p = {feat_all, EM, W_opT, EM, EM};
      gemm_lds<1, float><<<dim3(20, VP2 / 128), 256, 0, stream>>>(
          V, p, ZP, b_op, nullptr, out, V); }
}

// Round 13
// 1440.559 us; speedup vs baseline: 1.0068x; 1.0068x over previous
//
#include <hip/hip_runtime.h>
#include <hip/hip_bf16.h>

// Problem constants
#define B 128
#define S 196
#define E 2048
#define D 512
#define A 256
#define V 10000
#define EM 512
#define T 20
#define KCAT 2560         // ctx(2048) + h(512) concatenated K for gates

typedef unsigned short u16;
typedef __bf16 bf16x8 __attribute__((ext_vector_type(8)));
typedef float f32x4 __attribute__((ext_vector_type(4)));
typedef u16 u16x8 __attribute__((ext_vector_type(8)));
typedef u16 u16x4 __attribute__((ext_vector_type(4)));

__device__ inline u16 f2bf(float f) {
    union { float f; unsigned u; } x; x.f = f;
    return (u16)((x.u + 0x7FFFu + ((x.u >> 16) & 1u)) >> 16);
}
__device__ inline float bf2f(u16 h) {
    union { unsigned u; float f; } x; x.u = ((unsigned)h) << 16;
    return x.f;
}
__device__ inline bf16x8 ld_bf8(const u16* p) {
    return __builtin_bit_cast(bf16x8, *reinterpret_cast<const u16x8*>(p));
}
__device__ inline bf16x8 cvt_bf8(const float* p) {
    float4 u = *reinterpret_cast<const float4*>(p);
    float4 v = *reinterpret_cast<const float4*>(p + 4);
    u16x8 t;
    t[0] = f2bf(u.x); t[1] = f2bf(u.y); t[2] = f2bf(u.z); t[3] = f2bf(u.w);
    t[4] = f2bf(v.x); t[5] = f2bf(v.y); t[6] = f2bf(v.z); t[7] = f2bf(v.w);
    return __builtin_bit_cast(bf16x8, t);
}
__device__ inline u16x8 cvt_u16x8(const float* p) {
    float4 u = *reinterpret_cast<const float4*>(p);
    float4 v = *reinterpret_cast<const float4*>(p + 4);
    u16x8 t;
    t[0] = f2bf(u.x); t[1] = f2bf(u.y); t[2] = f2bf(u.z); t[3] = f2bf(u.w);
    t[4] = f2bf(v.x); t[5] = f2bf(v.y); t[6] = f2bf(v.z); t[7] = f2bf(v.w);
    return t;
}
__device__ inline float sigm(float x) { return 1.f / (1.f + expf(-x)); }

// ===========================================================================
// Generic streaming MFMA bf16 GEMM (no LDS).
// ===========================================================================
struct PairT {
    const void* Ap;  // bf16 (u16*) or float* when AF32
    long lda;
    const u16* Bt;   // B^T [Npad][K] bf16
    long ldb;
    int K;           // multiple of 32
};

template <int NP, bool AF32, typename OutT, int WTM, int WTN, int WVM, int WVN,
          bool SWAPXY = false>
__global__ __launch_bounds__(WVM * WVN * 64) void gemm_mfma(
    int N, PairT q0, PairT q1, PairT q2,
    const float* __restrict__ bias1, const float* __restrict__ bias2,
    OutT* __restrict__ Cc, long ldc)
{
    const int tid  = threadIdx.x;
    const int w    = tid >> 6;
    const int lane = tid & 63;
    const int lr   = lane & 15;
    const int lg   = lane >> 4;
    const int mb   = SWAPXY ? blockIdx.x : blockIdx.y;
    const int nb   = SWAPXY ? blockIdx.y : blockIdx.x;
    const int mrow = mb * (WVM * WTM * 16) + (w / WVN) * (WTM * 16);
    const int ncol = nb * (WVN * WTN * 16) + (w % WVN) * (WTN * 16);

    f32x4 acc[WTM][WTN];
#pragma unroll
    for (int i = 0; i < WTM; ++i)
#pragma unroll
        for (int j = 0; j < WTN; ++j) acc[i][j] = (f32x4){0.f, 0.f, 0.f, 0.f};

    const PairT qs[3] = {q0, q1, q2};
#pragma unroll
    for (int p = 0; p < NP; ++p) {
        const PairT pp = qs[p];
        const int nk = pp.K >> 5;
        const u16*   Ab = (const u16*)pp.Ap;
        const float* Af = (const float*)pp.Ap;
        size_t aoff[WTM];
#pragma unroll
        for (int mi = 0; mi < WTM; ++mi)
            aoff[mi] = (size_t)(mrow + mi * 16 + lr) * pp.lda + lg * 8;
        const u16* Bp = pp.Bt + (size_t)(ncol + lr) * pp.ldb + lg * 8;

#pragma unroll 2
        for (int kk = 0; kk < nk; ++kk) {
            const int ko = kk * 32;
            bf16x8 av[WTM], bv[WTN];
#pragma unroll
            for (int mi = 0; mi < WTM; ++mi) {
                if (AF32) av[mi] = cvt_bf8(Af + aoff[mi] + ko);
                else      av[mi] = ld_bf8(Ab + aoff[mi] + ko);
            }
#pragma unroll
            for (int ni = 0; ni < WTN; ++ni)
                bv[ni] = ld_bf8(Bp + ko + (size_t)(ni * 16) * pp.ldb);
#pragma unroll
            for (int mi = 0; mi < WTM; ++mi)
#pragma unroll
                for (int ni = 0; ni < WTN; ++ni)
                    acc[mi][ni] = __builtin_amdgcn_mfma_f32_16x16x32_bf16(
                        av[mi], bv[ni], acc[mi][ni], 0, 0, 0);
        }
    }

#pragma unroll
    for (int ni = 0; ni < WTN; ++ni) {
        const int col = ncol + ni * 16 + lr;
        if (col >= N) continue;
        float bs = 0.f;
        if (bias1) bs += bias1[col];
        if (bias2) bs += bias2[col];
#pragma unroll
        for (int mi = 0; mi < WTM; ++mi) {
#pragma unroll
            for (int r = 0; r < 4; ++r) {
                const int row = mrow + mi * 16 + lg * 4 + r;
                const float v = acc[mi][ni][r] + bs;
                if constexpr (sizeof(OutT) == 2)
                    Cc[(size_t)row * ldc + col] = (OutT)f2bf(v);
                else
                    Cc[(size_t)row * ldc + col] = v;
            }
        }
    }
}

// ===========================================================================
// Generic LDS-staged 128x128 GEMM (BK=64, 4 waves 2x2, XOR swizzle).
// grid = (M/128, N/128). Up to 2 fused pairs (K multiple of 64), 2 biases.
// GATHER: A rows are table[captions[row]] (fp32, converted in-register).
// ===========================================================================
template <int NP, typename OutT, bool GATHER = false>
__global__ __launch_bounds__(256) void gemm_lds(
    int N, PairT q0, PairT q1,
    const int* __restrict__ captions,   // used when GATHER
    const float* __restrict__ bias1, const float* __restrict__ bias2,
    OutT* __restrict__ Cc, long ldc)
{
    __shared__ u16 As[128 * 64];
    __shared__ u16 Bs[128 * 64];

    const int tid  = threadIdx.x;
    const int w    = tid >> 6;
    const int lane = tid & 63;
    const int lr   = lane & 15;
    const int lg   = lane >> 4;
    const int brow = blockIdx.x * 128;
    const int bcol = blockIdx.y * 128;
    const int wrow = (w >> 1) * 64;
    const int wcol = (w & 1) * 64;

    int arow[4], acb[4], aphys[4], agath[4];
#pragma unroll
    for (int i = 0; i < 4; ++i) {
        const int s = (tid + 256 * i) * 16;
        arow[i]  = s >> 7;
        acb[i]   = s & 127;
        aphys[i] = (s ^ ((arow[i] & 7) << 4)) >> 1;
        agath[i] = GATHER ? captions[brow + arow[i]] : 0;
    }

    int aoff[2][4], boff[2][4];
#pragma unroll
    for (int kh = 0; kh < 2; ++kh) {
#pragma unroll
        for (int i = 0; i < 4; ++i) {
            const int ra = wrow + i * 16 + lr;
            aoff[kh][i] = (((ra << 7) + (kh << 6) + (lg << 4)) ^ ((ra & 7) << 4)) >> 1;
            const int rb = wcol + i * 16 + lr;
            boff[kh][i] = (((rb << 7) + (kh << 6) + (lg << 4)) ^ ((rb & 7) << 4)) >> 1;
        }
    }

    f32x4 acc[4][4];
#pragma unroll
    for (int i = 0; i < 4; ++i)
#pragma unroll
        for (int j = 0; j < 4; ++j) acc[i][j] = (f32x4){0.f, 0.f, 0.f, 0.f};

    const PairT qs[2] = {q0, q1};
#pragma unroll
    for (int p = 0; p < NP; ++p) {
        const u16*   Ab = (const u16*)qs[p].Ap;
        const float* Af = (const float*)qs[p].Ap;
        const u16* Bt = qs[p].Bt;
        const long lda = qs[p].lda;
        const long ldb = qs[p].ldb;
        const int  K   = qs[p].K;

        for (int k0 = 0; k0 < K; k0 += 64) {
            u16x8 av[4], bv[4];
#pragma unroll
            for (int i = 0; i < 4; ++i) {
                if (GATHER)
                    av[i] = cvt_u16x8(Af + (size_t)agath[i] * lda + k0 + (acb[i] >> 1));
                else
                    av[i] = *reinterpret_cast<const u16x8*>(
                        Ab + (size_t)(brow + arow[i]) * lda + k0 + (acb[i] >> 1));
                bv[i] = *reinterpret_cast<const u16x8*>(
                    Bt + (size_t)(bcol + arow[i]) * ldb + k0 + (acb[i] >> 1));
            }
            __syncthreads();
#pragma unroll
            for (int i = 0; i < 4; ++i) {
                *reinterpret_cast<u16x8*>(As + aphys[i]) = av[i];
                *reinterpret_cast<u16x8*>(Bs + aphys[i]) = bv[i];
            }
            __syncthreads();

#pragma unroll
            for (int kh = 0; kh < 2; ++kh) {
                bf16x8 af[4], bf_[4];
#pragma unroll
                for (int mi = 0; mi < 4; ++mi)
                    af[mi] = __builtin_bit_cast(bf16x8,
                        *reinterpret_cast<const u16x8*>(As + aoff[kh][mi]));
#pragma unroll
                for (int ni = 0; ni < 4; ++ni)
                    bf_[ni] = __builtin_bit_cast(bf16x8,
                        *reinterpret_cast<const u16x8*>(Bs + boff[kh][ni]));
#pragma unroll
                for (int mi = 0; mi < 4; ++mi)
#pragma unroll
                    for (int ni = 0; ni < 4; ++ni)
                        acc[mi][ni] = __builtin_amdgcn_mfma_f32_16x16x32_bf16(
                            af[mi], bf_[ni], acc[mi][ni], 0, 0, 0);
            }
        }
    }

#pragma unroll
    for (int ni = 0; ni < 4; ++ni) {
        const int col = bcol + wcol + ni * 16 + lr;
        if (col >= N) continue;
        float bs = 0.f;
        if (bias1) bs += bias1[col];
        if (bias2) bs += bias2[col];
#pragma unroll
        for (int mi = 0; mi < 4; ++mi) {
#pragma unroll
            for (int r = 0; r < 4; ++r) {
                const int row = brow + wrow + mi * 16 + lg * 4 + r;
                const float v = acc[mi][ni][r] + bs;
                if constexpr (sizeof(OutT) == 2)
                    Cc[(size_t)row * ldc + col] = (OutT)f2bf(v);
                else
                    Cc[(size_t)row * ldc + col] = v;
            }
        }
    }
}

// ===========================================================================
// enc_att LDS-staged GEMM (proven v1): C[M][256] = A[M][2048] @ Bt^T + bias.
// grid = (2, M/128), 256 threads.
// ===========================================================================
__global__ __launch_bounds__(256) void gemm_enc(
    const u16* __restrict__ Abf,   // [M][2048] bf16
    const u16* __restrict__ Bt,    // [256][2048] bf16
    const float* __restrict__ bias,
    u16* __restrict__ Cc)          // [M][256] bf16
{
    __shared__ u16 As[128 * 64];
    __shared__ u16 Bs[128 * 64];

    const int tid  = threadIdx.x;
    const int w    = tid >> 6;
    const int lane = tid & 63;
    const int lr   = lane & 15;
    const int lg   = lane >> 4;
    const int brow = blockIdx.y * 128;
    const int bcol = blockIdx.x * 128;
    const int wrow = (w >> 1) * 64;
    const int wcol = (w & 1) * 64;

    int arow[4], acb[4], aphys[4];
#pragma unroll
    for (int i = 0; i < 4; ++i) {
        const int s = (tid + 256 * i) * 16;
        arow[i]  = s >> 7;
        acb[i]   = s & 127;
        aphys[i] = (s ^ ((arow[i] & 7) << 4)) >> 1;
    }

    int aoff[2][4], boff[2][4];
#pragma unroll
    for (int kh = 0; kh < 2; ++kh) {
#pragma unroll
        for (int i = 0; i < 4; ++i) {
            const int ra = wrow + i * 16 + lr;
            aoff[kh][i] = (((ra << 7) + (kh << 6) + (lg << 4)) ^ ((ra & 7) << 4)) >> 1;
            const int rb = wcol + i * 16 + lr;
            boff[kh][i] = (((rb << 7) + (kh << 6) + (lg << 4)) ^ ((rb & 7) << 4)) >> 1;
        }
    }

    f32x4 acc[4][4];
#pragma unroll
    for (int i = 0; i < 4; ++i)
#pragma unroll
        for (int j = 0; j < 4; ++j) acc[i][j] = (f32x4){0.f, 0.f, 0.f, 0.f};

    for (int k0 = 0; k0 < 2048; k0 += 64) {
        u16x8 av[4], bv[4];
#pragma unroll
        for (int i = 0; i < 4; ++i) {
            av[i] = *reinterpret_cast<const u16x8*>(
                Abf + (size_t)(brow + arow[i]) * 2048 + k0 + (acb[i] >> 1));
            bv[i] = *reinterpret_cast<const u16x8*>(
                Bt + (size_t)(bcol + arow[i]) * 2048 + k0 + (acb[i] >> 1));
        }
        __syncthreads();
#pragma unroll
        for (int i = 0; i < 4; ++i) {
            *reinterpret_cast<u16x8*>(As + aphys[i]) = av[i];
            *reinterpret_cast<u16x8*>(Bs + aphys[i]) = bv[i];
        }
        __syncthreads();

#pragma unroll
        for (int kh = 0; kh < 2; ++kh) {
            bf16x8 af[4], bf_[4];
#pragma unroll
            for (int mi = 0; mi < 4; ++mi)
                af[mi] = __builtin_bit_cast(bf16x8,
                    *reinterpret_cast<const u16x8*>(As + aoff[kh][mi]));
#pragma unroll
            for (int ni = 0; ni < 4; ++ni)
                bf_[ni] = __builtin_bit_cast(bf16x8,
                    *reinterpret_cast<const u16x8*>(Bs + boff[kh][ni]));
#pragma unroll
            for (int mi = 0; mi < 4; ++mi)
#pragma unroll
                for (int ni = 0; ni < 4; ++ni)
                    acc[mi][ni] = __builtin_amdgcn_mfma_f32_16x16x32_bf16(
                        af[mi], bf_[ni], acc[mi][ni], 0, 0, 0);
        }
    }

#pragma unroll
    for (int ni = 0; ni < 4; ++ni) {
        const int col = bcol + wcol + ni * 16 + lr;
        const float bs = bias[col];
#pragma unroll
        for (int mi = 0; mi < 4; ++mi) {
#pragma unroll
            for (int r = 0; r < 4; ++r) {
                const int row = brow + wrow + mi * 16 + lg * 4 + r;
                Cc[(size_t)row * 256 + col] = f2bf(acc[mi][ni][r] + bs);
            }
        }
    }
}

// ===========================================================================
// init xin h-section = h0 (gates kernel reads it at t=0)
// ===========================================================================
__global__ __launch_bounds__(256) void init_xin_h(
    const u16* __restrict__ h_cur, u16* __restrict__ xin)
{
    const int idx = blockIdx.x * 256 + threadIdx.x;  // B*D
    const int b = idx >> 9;
    const int d = idx & (D - 1);
    xin[(size_t)b * KCAT + 2048 + d] = h_cur[idx];
}

// ===========================================================================
// K1: fused [LSTM-finish(t-1)] + dec_att + scores + softmax + context(t).
// grid = 256 blocks (pair per batch row), 256 threads.
// ===========================================================================
template <bool FBF>
__global__ __launch_bounds__(256) void alpha_ctx_lstm(
    const void* __restrict__ Fv,        // F_bf (u16) or F (float)
    const u16*  __restrict__ enc,       // [B*S][A]
    const u16*  __restrict__ W_daT,     // [A][D]
    const float* __restrict__ b_da,
    const float* __restrict__ W_fa,
    const float* __restrict__ b_ih_,
    const float* __restrict__ b_hh_,
    const float* __restrict__ egates,   // [B*T][2048] fp32 (interleaved cols)
    const float* __restrict__ part,     // [4][B][2048] split-K partials
    const float* __restrict__ c_rd,
    float* __restrict__ c_wr,
    const u16*  __restrict__ h0,        // initial h (used at t==0)
    u16* __restrict__ h_all,            // [B*T][D]
    u16* __restrict__ ctx_all,          // [B*T][E]
    u16* __restrict__ xin,              // [B][KCAT]
    int t)
{
    const int blk  = blockIdx.x;
    const int tid  = threadIdx.x;
    const int w    = tid >> 6;
    const int lane = tid & 63;
    const int b    = blk >> 1;
    const int q    = blk & 1;

    __shared__ float hl[D];
    __shared__ float dec[A];
    __shared__ float wfa[A];
    __shared__ float sc[S];
    __shared__ float red[8];

    if (t == 0) {
        hl[tid]       = bf2f(h0[b * D + tid]);
        hl[tid + 256] = bf2f(h0[b * D + 256 + tid]);
    } else {
        const int tt = t - 1;
#pragma unroll
        for (int half = 0; half < 2; ++half) {
            const int d = tid + half * 256;
            float g4[4];
#pragma unroll
            for (int g = 0; g < 4; ++g) {
                const int col = ((d >> 4) << 6) + (g << 4) + (d & 15);
                float s = b_ih_[g * D + d] + b_hh_[g * D + d] +
                          egates[((size_t)(b * T + tt) << 11) + col];
#pragma unroll
                for (int z = 0; z < 4; ++z)
                    s += part[((size_t)(z * B + b) << 11) + col];
                g4[g] = s;
            }
            const int idx = (b << 9) + d;
            const float cn = sigm(g4[1]) * c_rd[idx] + sigm(g4[0]) * tanhf(g4[2]);
            const float hf = sigm(g4[3]) * tanhf(cn);
            hl[d] = hf;
            if (q == 0) {
                c_wr[idx] = cn;
                const u16 hv = f2bf(hf);
                h_all[((size_t)(b * T + tt)) * D + d] = hv;
                xin[(size_t)b * KCAT + 2048 + d] = hv;
            }
        }
    }
    wfa[tid] = W_fa[tid];
    __syncthreads();

    // dec[a] = h . W_da[:,a] + b_da[a]  (redundant across the pair)
    {
        float acc = 0.f;
        const u16* wr = W_daT + (size_t)tid * D;
#pragma unroll 4
        for (int i = 0; i < D / 8; ++i) {
            const u16x8 v = *reinterpret_cast<const u16x8*>(wr + i * 8);
#pragma unroll
            for (int j = 0; j < 8; ++j) acc += bf2f(v[j]) * hl[i * 8 + j];
        }
        dec[tid] = acc + b_da[tid];
    }
    __syncthreads();

    // scores (b_fa dropped: softmax shift-invariant)
    if (tid < S) {
        const u16* er = enc + ((size_t)b * S + tid) * A;
        float v = 0.f;
#pragma unroll 4
        for (int i = 0; i < A / 8; ++i) {
            const u16x8 e8 = *reinterpret_cast<const u16x8*>(er + i * 8);
#pragma unroll
            for (int j = 0; j < 8; ++j) {
                float x = bf2f(e8[j]) + dec[i * 8 + j];
                x = x > 0.f ? x : 0.f;
                v += x * wfa[i * 8 + j];
            }
        }
        sc[tid] = v;
    }
    __syncthreads();

    float m = -1e30f;
    for (int s = tid; s < S; s += 256) m = fmaxf(m, sc[s]);
    for (int off = 32; off; off >>= 1) m = fmaxf(m, __shfl_down(m, off));
    if (lane == 0) red[w] = m;
    __syncthreads();
    if (tid == 0) red[0] = fmaxf(fmaxf(red[0], red[1]), fmaxf(red[2], red[3]));
    __syncthreads();
    m = red[0];

    float sum = 0.f;
    for (int s = tid; s < S; s += 256) {
        const float ev = __expf(sc[s] - m);
        sc[s] = ev;
        sum += ev;
    }
    for (int off = 32; off; off >>= 1) sum += __shfl_down(sum, off);
    if (lane == 0) red[4 + w] = sum;
    __syncthreads();
    if (tid == 0) red[4] = red[4] + red[5] + red[6] + red[7];
    __syncthreads();
    const float inv = 1.f / red[4];

    // context: e = q*1024 + tid*4 ; 4 s-streams of 49 (28 loads in flight)
    {
        const int e0 = q * 1024 + tid * 4;
        float a0 = 0.f, a1 = 0.f, a2 = 0.f, a3 = 0.f;
        float b0 = 0.f, b1 = 0.f, b2 = 0.f, b3 = 0.f;
        float c0 = 0.f, c1 = 0.f, c2 = 0.f, c3 = 0.f;
        float d0 = 0.f, d1 = 0.f, d2 = 0.f, d3 = 0.f;
        if (FBF) {
            const u16* F0 = (const u16*)Fv + (size_t)b * S * E + e0;
            const u16* F1 = F0 + (size_t)49 * E;
            const u16* F2 = F0 + (size_t)98 * E;
            const u16* F3 = F0 + (size_t)147 * E;
#pragma unroll 7
            for (int s = 0; s < 49; ++s) {
                const u16x4 v0 = *reinterpret_cast<const u16x4*>(F0 + (size_t)s * E);
                const u16x4 v1 = *reinterpret_cast<const u16x4*>(F1 + (size_t)s * E);
                const u16x4 v2 = *reinterpret_cast<const u16x4*>(F2 + (size_t)s * E);
                const u16x4 v3 = *reinterpret_cast<const u16x4*>(F3 + (size_t)s * E);
                const float l0 = sc[s], l1 = sc[s + 49], l2 = sc[s + 98], l3 = sc[s + 147];
                a0 += l0 * bf2f(v0[0]); a1 += l0 * bf2f(v0[1]);
                a2 += l0 * bf2f(v0[2]); a3 += l0 * bf2f(v0[3]);
                b0 += l1 * bf2f(v1[0]); b1 += l1 * bf2f(v1[1]);
                b2 += l1 * bf2f(v1[2]); b3 += l1 * bf2f(v1[3]);
                c0 += l2 * bf2f(v2[0]); c1 += l2 * bf2f(v2[1]);
                c2 += l2 * bf2f(v2[2]); c3 += l2 * bf2f(v2[3]);
                d0 += l3 * bf2f(v3[0]); d1 += l3 * bf2f(v3[1]);
                d2 += l3 * bf2f(v3[2]); d3 += l3 * bf2f(v3[3]);
            }
        } else {
            const float* F0 = (const float*)Fv + (size_t)b * S * E + e0;
            const float* F1 = F0 + (size_t)49 * E;
            const float* F2 = F0 + (size_t)98 * E;
            const float* F3 = F0 + (size_t)147 * E;
#pragma unroll 7
            for (int s = 0; s < 49; ++s) {
                const float4 v0 = *reinterpret_cast<const float4*>(F0 + (size_t)s * E);
                const float4 v1 = *reinterpret_cast<const float4*>(F1 + (size_t)s * E);
                const float4 v2 = *reinterpret_cast<const float4*>(F2 + (size_t)s * E);
                const float4 v3 = *reinterpret_cast<const float4*>(F3 + (size_t)s * E);
                const float l0 = sc[s], l1 = sc[s + 49], l2 = sc[s + 98], l3 = sc[s + 147];
                a0 += l0 * v0.x; a1 += l0 * v0.y; a2 += l0 * v0.z; a3 += l0 * v0.w;
                b0 += l1 * v1.x; b1 += l1 * v1.y; b2 += l1 * v1.z; b3 += l1 * v1.w;
                c0 += l2 * v2.x; c1 += l2 * v2.y; c2 += l2 * v2.z; c3 += l2 * v2.w;
                d0 += l3 * v3.x; d1 += l3 * v3.y; d2 += l3 * v3.z; d3 += l3 * v3.w;
            }
        }
        a0 += b0 + c0 + d0; a1 += b1 + c1 + d1;
        a2 += b2 + c2 + d2; a3 += b3 + c3 + d3;
        u16x4 o;
        o[0] = f2bf(a0 * inv); o[1] = f2bf(a1 * inv);
        o[2] = f2bf(a2 * inv); o[3] = f2bf(a3 * inv);
        *reinterpret_cast<u16x4*>(ctx_all + ((size_t)(b * T + t)) * E + e0) = o;
        *reinterpret_cast<u16x4*>(xin + (size_t)b * KCAT + e0) = o;
    }
}

// ===========================================================================
// K2: gates split-K4 over xin=[ctx;h] (KCAT=2560, 4 chunks of 640) vs W_chT.
// Wave tile 16M x 64N, 2 waves/block. grid = (16, 8, 4), 128 threads.
// ===========================================================================
__global__ __launch_bounds__(128) void gates_split4(
    const u16* __restrict__ xin, const u16* __restrict__ W_chT,
    float* __restrict__ part)
{
    const int tid  = threadIdx.x;
    const int w    = tid >> 6;
    const int lane = tid & 63;
    const int lr   = lane & 15;
    const int lg   = lane >> 4;
    const int mrow = blockIdx.y * 16;
    const int ncol = blockIdx.x * 128 + w * 64;
    const int z    = blockIdx.z;
    const int kb   = z * 640;

    f32x4 acc[4];
#pragma unroll
    for (int j = 0; j < 4; ++j) acc[j] = (f32x4){0.f, 0.f, 0.f, 0.f};

    const u16* Ap = xin + (size_t)(mrow + lr) * KCAT + kb + lg * 8;
    const u16* Bp = W_chT + (size_t)(ncol + lr) * KCAT + kb + lg * 8;

#pragma unroll 4
    for (int kk = 0; kk < 20; ++kk) {
        const int ko = kk * 32;
        const bf16x8 av = ld_bf8(Ap + ko);
        bf16x8 bv[4];
#pragma unroll
        for (int ni = 0; ni < 4; ++ni)
            bv[ni] = ld_bf8(Bp + ko + (size_t)(ni * 16) * KCAT);
#pragma unroll
        for (int ni = 0; ni < 4; ++ni)
            acc[ni] = __builtin_amdgcn_mfma_f32_16x16x32_bf16(av, bv[ni], acc[ni], 0, 0, 0);
    }

#pragma unroll
    for (int ni = 0; ni < 4; ++ni) {
        const int col = ncol + ni * 16 + lr;
#pragma unroll
        for (int r = 0; r < 4; ++r) {
            const int row = mrow + lg * 4 + r;
            part[((size_t)(z * B + row) << 11) + col] = acc[ni][r];
        }
    }
}

// ===========================================================================
// lstm_last: LSTM finish for t = T-1 (only h_all needed). grid = 256.
// ===========================================================================
__global__ __launch_bounds__(256) void lstm_last(
    const float* __restrict__ part,
    const float* __restrict__ egates,
    const float* __restrict__ b_ih_, const float* __restrict__ b_hh_,
    const float* __restrict__ c_rd,
    u16* __restrict__ h_all)
{
    const int idx = blockIdx.x * 256 + threadIdx.x;  // B*D
    const int b = idx >> 9;
    const int d = idx & (D - 1);
    const int tt = T - 1;
    float g4[4];
#pragma unroll
    for (int g = 0; g < 4; ++g) {
        const int col = ((d >> 4) << 6) + (g << 4) + (d & 15);
        float s = b_ih_[g * D + d] + b_hh_[g * D + d] +
                  egates[((size_t)(b * T + tt) << 11) + col];
#pragma unroll
        for (int z = 0; z < 4; ++z)
            s += part[((size_t)(z * B + b) << 11) + col];
        g4[g] = s;
    }
    const float cn = sigm(g4[1]) * c_rd[idx] + sigm(g4[0]) * tanhf(g4[2]);
    h_all[((size_t)(b * T + tt)) * D + d] = f2bf(sigm(g4[3]) * tanhf(cn));
}

// ===========================================================================
// Fused weight transposes: one launch, segment table.
// ===========================================================================
struct TSeg {
    const float* src; u16* dst;
    int K; int N; int ldo; int ko; int mode; int tilesX; int nblk;
};
struct TransArgs { TSeg seg[10]; };

__global__ __launch_bounds__(256) void transpose_all(TransArgs a)
{
    __shared__ float tls[32][33];
    int bid = blockIdx.x;
    int si = 0;
    while (si < 9 && bid >= a.seg[si].nblk) { bid -= a.seg[si].nblk; ++si; }
    const TSeg s = a.seg[si];
    const int n0 = (bid % s.tilesX) * 32;
    const int k0 = (bid / s.tilesX) * 32;
    const int c  = threadIdx.x & 31;
    const int r8 = threadIdx.x >> 5;

#pragma unroll
    for (int i = 0; i < 4; ++i) {
        const int k = r8 + i * 8;
        float v = 0.f;
        if (n0 + c < s.N) v = s.src[(size_t)(k0 + k) * s.N + n0 + c];
        tls[k][c] = v;
    }
    __syncthreads();
#pragma unroll
    for (int i = 0; i < 4; ++i) {
        const int nn = r8 + i * 8;
        const int n = n0 + nn;
        int row;
        if (s.mode) {
            const int g = n >> 9, d = n & (D - 1);
            row = ((d >> 4) << 6) + (g << 4) + (d & 15);
        } else {
            row = n;
        }
        s.dst[(size_t)row * s.ldo + s.ko + k0 + c] = f2bf(tls[c][nn]);
    }
}

// ===========================================================================
// fused: mean over S (fp32 acc -> bf16) and optional F -> bf16 copy
// ===========================================================================
template <bool WRITE>
__global__ __launch_bounds__(256) void conv_mean(
    const float* __restrict__ F, u16* __restrict__ Fbf, u16* __restrict__ meanbf)
{
    const int idx = blockIdx.x * 256 + threadIdx.x;  // over B*E
    const int b = idx >> 11;
    const int e = idx & (E - 1);
    const float* src = F + (size_t)b * S * E + e;
    float acc = 0.f;
#pragma unroll 8
    for (int s = 0; s < S; ++s) {
        const float v = src[(size_t)s * E];
        acc += v;
        if (WRITE) Fbf[(size_t)b * S * E + (size_t)s * E + e] = f2bf(v);
    }
    meanbf[idx] = f2bf(acc * (1.f / (float)S));
}

// ===========================================================================
// ======================= fp32 fallback path ================================
// ===========================================================================
struct Pair {
    const float* Aptr; int lda; const float* Wptr; int ldw; int K;
};

template <int NP>
__global__ __launch_bounds__(256) void gemm_f32(
    int M, int N, Pair p0, Pair p1, Pair p2,
    const float* __restrict__ bias1, const float* __restrict__ bias2,
    float* __restrict__ C, long ldc)
{
    __shared__ float As[64][17];
    __shared__ float Ws[16][64];
    const int tid = threadIdx.x;
    const int row0 = blockIdx.y * 64, col0 = blockIdx.x * 64;
    const int tx = tid & 15, ty = tid >> 4;
    float acc[4][4] = {};
    Pair ps[3] = {p0, p1, p2};
#pragma unroll
    for (int p = 0; p < NP; ++p) {
        const float* Ag = ps[p].Aptr; const float* Wg = ps[p].Wptr;
        const int lda = ps[p].lda, ldw = ps[p].ldw, K = ps[p].K;
        for (int k0 = 0; k0 < K; k0 += 16) {
            {
                const int k = tid & 15, mb = tid >> 4;
#pragma unroll
                for (int i = 0; i < 4; ++i) {
                    const int m = mb + 16 * i, gr = row0 + m;
                    float v = 0.f;
                    if (gr < M) v = Ag[(size_t)gr * lda + k0 + k];
                    As[m][k] = v;
                }
            }
            {
                const int n = tid & 63, kb = tid >> 6, gc = col0 + n;
#pragma unroll
                for (int i = 0; i < 4; ++i) {
                    const int k = kb * 4 + i;
                    float v = 0.f;
                    if (gc < N) v = Wg[(size_t)(k0 + k) * ldw + gc];
                    Ws[k][n] = v;
                }
            }
            __syncthreads();
#pragma unroll
            for (int k = 0; k < 16; ++k) {
                float av[4];
#pragma unroll
                for (int i = 0; i < 4; ++i) av[i] = As[ty * 4 + i][k];
                const float4 bv = reinterpret_cast<const float4*>(&Ws[k][0])[tx];
                const float bvv[4] = {bv.x, bv.y, bv.z, bv.w};
#pragma unroll
                for (int i = 0; i < 4; ++i)
#pragma unroll
                    for (int j = 0; j < 4; ++j) acc[i][j] += av[i] * bvv[j];
            }
            __syncthreads();
        }
    }
#pragma unroll
    for (int i = 0; i < 4; ++i) {
        const int r = row0 + ty * 4 + i;
        if (r >= M) continue;
#pragma unroll
        for (int j = 0; j < 4; ++j) {
            const int cidx = col0 + tx * 4 + j;
            if (cidx >= N) continue;
            float v = acc[i][j];
            if (bias1) v += bias1[cidx];
            if (bias2) v += bias2[cidx];
            C[(size_t)r * ldc + cidx] = v;
        }
    }
}

__global__ __launch_bounds__(256) void mean_pool(const float* __restrict__ F,
                                                 float* __restrict__ mean)
{
    const int idx = blockIdx.x * 256 + threadIdx.x;
    const int b = idx >> 11, e = idx & (E - 1);
    const float* Fb = F + (size_t)b * S * E + e;
    float acc = 0.f;
    for (int s = 0; s < S; ++s) acc += Fb[(size_t)s * E];
    mean[idx] = acc * (1.f / (float)S);
}

__global__ __launch_bounds__(256) void gather_embs(const int* __restrict__ captions,
                                                   const float* __restrict__ table,
                                                   float* __restrict__ out)
{
    const int idx = blockIdx.x * 256 + threadIdx.x;
    const int per_row = EM / 4;
    const int row = idx / per_row;
    const int col = idx - row * per_row;
    const int cap = captions[row];
    reinterpret_cast<float4*>(out)[idx] =
        reinterpret_cast<const float4*>(table + (size_t)cap * EM)[col];
}

__global__ __launch_bounds__(256) void attn_softmax(
    const float* __restrict__ enc_att, const float* __restrict__ dec_att,
    const float* __restrict__ W_fa, const float* __restrict__ b_fa,
    float* __restrict__ alpha)
{
    const int b = blockIdx.x, tid = threadIdx.x;
    const int wave = tid >> 6, lane = tid & 63;
    __shared__ float dec[A], wfa[A], sc[S], redm[4], reds[4];
    dec[tid] = dec_att[b * A + tid];
    wfa[tid] = W_fa[tid];
    __syncthreads();
    for (int s = wave; s < S; s += 4) {
        const float* ea = enc_att + ((size_t)b * S + s) * A;
        float v = 0.f;
#pragma unroll
        for (int i = 0; i < 4; ++i) {
            const int a = lane + 64 * i;
            float x = ea[a] + dec[a];
            x = x > 0.f ? x : 0.f;
            v += x * wfa[a];
        }
        for (int off = 32; off; off >>= 1) v += __shfl_down(v, off);
        if (lane == 0) sc[s] = v + b_fa[0];
    }
    __syncthreads();
    float m = -1e30f;
    for (int s = tid; s < S; s += 256) m = fmaxf(m, sc[s]);
    for (int off = 32; off; off >>= 1) m = fmaxf(m, __shfl_down(m, off));
    if (lane == 0) redm[wave] = m;
    __syncthreads();
    if (tid == 0) redm[0] = fmaxf(fmaxf(redm[0], redm[1]), fmaxf(redm[2], redm[3]));
    __syncthreads();
    m = redm[0];
    float sum = 0.f;
    for (int s = tid; s < S; s += 256) {
        const float ev = expf(sc[s] - m);
        sc[s] = ev; sum += ev;
    }
    for (int off = 32; off; off >>= 1) sum += __shfl_down(sum, off);
    if (lane == 0) reds[wave] = sum;
    __syncthreads();
    if (tid == 0) reds[0] = reds[0] + reds[1] + reds[2] + reds[3];
    __syncthreads();
    const float inv = 1.f / reds[0];
    for (int s = tid; s < S; s += 256) alpha[b * S + s] = sc[s] * inv;
}

__global__ __launch_bounds__(256) void context_kernel(
    const float* __restrict__ F, const float* __restrict__ alpha,
    float* __restrict__ ctx)
{
    const int chunks = E / 256;
    const int b = blockIdx.x / chunks;
    const int ec = blockIdx.x - b * chunks;
    const int e = ec * 256 + threadIdx.x;
    __shared__ float al[S];
    for (int s = threadIdx.x; s < S; s += 256) al[s] = alpha[b * S + s];
    __syncthreads();
    const float* Fb = F + (size_t)b * S * E + e;
    float acc = 0.f;
    for (int s = 0; s < S; ++s) acc += al[s] * Fb[(size_t)s * E];
    ctx[b * E + e] = acc;
}

__global__ __launch_bounds__(256) void lstm_cell(
    const float* __restrict__ gates, float* __restrict__ h, float* __restrict__ c)
{
    const int idx = blockIdx.x * 256 + threadIdx.x;
    const int b = idx >> 9, d = idx & (D - 1);
    const float* g = gates + (size_t)b * 4 * D;
    const float gi = g[d], gf = g[D + d], gg = g[2 * D + d], go = g[3 * D + d];
    const float cn = sigm(gf) * c[idx] + sigm(gi) * tanhf(gg);
    c[idx] = cn;
    h[idx] = sigm(go) * tanhf(cn);
}

// ===========================================================================
// launch
// ===========================================================================
extern "C" void kernel_launch(void* const* d_in, const int* in_sizes, int n_in,
                              void* d_out, int out_size, void* d_ws, size_t ws_size,
                              hipStream_t stream)
{
    const float* F        = (const float*)d_in[0];
    const int*   captions = (const int*)  d_in[1];
    const float* table    = (const float*)d_in[2];
    const float* W_ea     = (const float*)d_in[3];
    const float* b_ea     = (const float*)d_in[4];
    const float* W_da     = (const float*)d_in[5];
    const float* b_da     = (const float*)d_in[6];
    const float* W_fa     = (const float*)d_in[7];
    const float* b_fa     = (const float*)d_in[8];
    const float* W_ih     = (const float*)d_in[9];
    const float* b_ih     = (const float*)d_in[10];
    const float* W_hh     = (const float*)d_in[11];
    const float* b_hh     = (const float*)d_in[12];
    const float* W_cp     = (const float*)d_in[13];
    const float* b_cp     = (const float*)d_in[14];
    const float* W_hp     = (const float*)d_in[15];
    const float* b_hp     = (const float*)d_in[16];
    const float* W_op     = (const float*)d_in[17];
    const float* b_op     = (const float*)d_in[18];
    const float* W_inith  = (const float*)d_in[19];
    const float* b_inith  = (const float*)d_in[20];
    const float* W_initc  = (const float*)d_in[21];
    const float* b_initc  = (const float*)d_in[22];

    float* out = (float*)d_out;
    const int VP2 = 10240;  // V padded to 128-span

    // ---- workspace allocator (256 B aligned) ----
    char* base = (char*)d_ws;
    size_t off = 0;
    auto alloc = [&](size_t bytes) -> void* {
        off = (off + 255) & ~(size_t)255;
        void* p = base + off;
        off += bytes;
        return p;
    };

    u16* W_eaT    = (u16*)alloc((size_t)A * E * 2);
    u16* W_daT    = (u16*)alloc((size_t)A * D * 2);
    u16* W_iheT   = (u16*)alloc((size_t)2048 * EM * 2);     // emb section, interleaved
    u16* W_chT    = (u16*)alloc((size_t)2048 * KCAT * 2);   // [ctx;h] section, interleaved
    u16* W_cpT    = (u16*)alloc((size_t)EM * E * 2);
    u16* W_hpT    = (u16*)alloc((size_t)EM * D * 2);
    u16* W_opT    = (u16*)alloc((size_t)VP2 * EM * 2);
    u16* W_inithT = (u16*)alloc((size_t)D * E * 2);
    u16* W_initcT = (u16*)alloc((size_t)D * E * 2);
    u16* mean_bf  = (u16*)alloc((size_t)B * E * 2);
    u16* h_cur    = (u16*)alloc((size_t)B * D * 2);         // h0
    u16* h_all    = (u16*)alloc((size_t)B * T * D * 2);
    u16* ctx_all  = (u16*)alloc((size_t)B * T * E * 2);
    u16* xin      = (u16*)alloc((size_t)B * KCAT * 2);
    u16* feat_all = (u16*)alloc((size_t)B * T * EM * 2);
    u16* enc_bf   = (u16*)alloc((size_t)B * S * A * 2);
    float* cbuf0  = (float*)alloc((size_t)B * D * 4);
    float* cbuf1  = (float*)alloc((size_t)B * D * 4);
    float* egates = (float*)alloc((size_t)B * T * 2048 * 4);
    float* part   = (float*)alloc((size_t)4 * B * 2048 * 4);
    const size_t need_base = off;
    u16* F_bf     = (u16*)alloc((size_t)B * S * E * 2);
    const size_t need_fbf = off;

    const bool ok_base = need_base <= ws_size;
    const bool ok_fbf  = need_fbf <= ws_size;

    if (!ok_base) {
        // ---------------- fp32 fallback ----------------
        float* ws = (float*)d_ws;
        float* mean_feat = ws;  ws += B * E;
        float* h         = ws;  ws += B * D;
        float* c         = ws;  ws += B * D;
        float* enc_att   = ws;  ws += (size_t)B * S * A;
        float* fembs     = ws;  ws += (size_t)B * T * EM;
        float* fdec      = ws;  ws += B * A;
        float* falpha    = ws;  ws += B * S;
        float* fctx      = ws;  ws += B * E;
        float* fgates    = ws;  ws += B * 4 * D;
        float* ffeat     = ws;  ws += B * EM;
        const Pair ZP = {nullptr, 0, nullptr, 0, 0};
        mean_pool<<<(B * E) / 256, 256, 0, stream>>>(F, mean_feat);
        { Pair p = {mean_feat, E, W_inith, D, E};
          gemm_f32<1><<<dim3(D / 64, B / 64), 256, 0, stream>>>(B, D, p, ZP, ZP, b_inith, nullptr, h, D); }
        { Pair p = {mean_feat, E, W_initc, D, E};
          gemm_f32<1><<<dim3(D / 64, B / 64), 256, 0, stream>>>(B, D, p, ZP, ZP, b_initc, nullptr, c, D); }
        { Pair p = {F, E, W_ea, A, E};
          gemm_f32<1><<<dim3(A / 64, (B * S) / 64), 256, 0, stream>>>(B * S, A, p, ZP, ZP, b_ea, nullptr, enc_att, A); }
        gather_embs<<<(B * T * (EM / 4)) / 256, 256, 0, stream>>>(captions, table, fembs);
        for (int t = 0; t < T; ++t) {
            { Pair p = {h, D, W_da, A, D};
              gemm_f32<1><<<dim3(A / 64, B / 64), 256, 0, stream>>>(B, A, p, ZP, ZP, b_da, nullptr, fdec, A); }
            attn_softmax<<<B, 256, 0, stream>>>(enc_att, fdec, W_fa, b_fa, falpha);
            context_kernel<<<B * (E / 256), 256, 0, stream>>>(F, falpha, fctx);
            { Pair p0 = {fembs + (size_t)t * EM, T * EM, W_ih, 4 * D, EM};
              Pair p1 = {fctx, E, W_ih + (size_t)EM * 4 * D, 4 * D, E};
              Pair p2 = {h, D, W_hh, 4 * D, D};
              gemm_f32<3><<<dim3((4 * D) / 64, B / 64), 256, 0, stream>>>(B, 4 * D, p0, p1, p2, b_ih, b_hh, fgates, 4 * D); }
            lstm_cell<<<(B * D) / 256, 256, 0, stream>>>(fgates, h, c);
            { Pair p0 = {fctx, E, W_cp, EM, E};
              Pair p1 = {h, D, W_hp, EM, D};
              gemm_f32<2><<<dim3(EM / 64, B / 64), 256, 0, stream>>>(B, EM, p0, p1, ZP, b_cp, b_hp, ffeat, EM); }
            { Pair p = {ffeat, EM, W_op, V, EM};
              gemm_f32<1><<<dim3((V + 63) / 64, B / 64), 256, 0, stream>>>(B, V, p, ZP, ZP, b_op, nullptr, out + (size_t)t * V, (long)T * V); }
        }
        return;
    }

    // ---------------- bf16 MFMA path ----------------
    const PairT ZP = {nullptr, 0, nullptr, 0, 0};

    // fused weight transposes: one launch
    {
        TransArgs ta;
        auto seg = [&](int i, const float* src, u16* dst, int K, int N,
                       int ldo, int ko, int mode, int tilesX) {
            ta.seg[i] = {src, dst, K, N, ldo, ko, mode, tilesX, tilesX * (K / 32)};
        };
        seg(0, W_ea,    W_eaT,    2048, 256,   2048, 0,    0, 8);
        seg(1, W_da,    W_daT,    512,  256,   512,  0,    0, 8);
        seg(2, W_ih,    W_iheT,   512,  2048,  512,  0,    1, 64);
        seg(3, W_ih + (size_t)EM * 2048, W_chT, 2048, 2048, KCAT, 0, 1, 64);
        seg(4, W_hh,    W_chT,    512,  2048,  KCAT, 2048, 1, 64);
        seg(5, W_cp,    W_cpT,    2048, 512,   2048, 0,    0, 16);
        seg(6, W_hp,    W_hpT,    512,  512,   512,  0,    0, 16);
        seg(7, W_op,    W_opT,    512,  10000, 512,  0,    0, 320);
        seg(8, W_inith, W_inithT, 2048, 512,   2048, 0,    0, 16);
        seg(9, W_initc, W_initcT, 2048, 512,   2048, 0,    0, 16);
        int tot = 0;
        for (int i = 0; i < 10; ++i) tot += ta.seg[i].nblk;
        transpose_all<<<tot, 256, 0, stream>>>(ta);
    }

    if (ok_fbf)
        conv_mean<true><<<(B * E) / 256, 256, 0, stream>>>(F, F_bf, mean_bf);
    else
        conv_mean<false><<<(B * E) / 256, 256, 0, stream>>>(F, nullptr, mean_bf);

    // h0 (bf16), c0 (fp32 -> cbuf1: LSTM(0) reads cbuf1)
    { PairT p = {mean_bf, E, W_inithT, E, E};
      gemm_mfma<1, false, u16, 2, 4, 1, 4><<<dim3(2, 4), 256, 0, stream>>>(
          D, p, ZP, ZP, b_inith, nullptr, h_cur, D); }
    { PairT p = {mean_bf, E, W_initcT, E, E};
      gemm_mfma<1, false, float, 2, 4, 1, 4><<<dim3(2, 4), 256, 0, stream>>>(
          D, p, ZP, ZP, b_initc, nullptr, cbuf1, D); }

    // initialize xin h-section with h0
    init_xin_h<<<(B * D) / 256, 256, 0, stream>>>(h_cur, xin);

    // enc_att (v1, measured best: grid (2, 392))
    if (ok_fbf) {
        gemm_enc<<<dim3(2, (B * S) / 128), 256, 0, stream>>>(F_bf, W_eaT, b_ea, enc_bf);
    } else {
        PairT p = {F, E, W_eaT, E, E};
        gemm_mfma<1, true, u16, 4, 4, 1, 4><<<dim3(1, (B * S) / 64), 256, 0, stream>>>(
            A, p, ZP, ZP, b_ea, nullptr, enc_bf, A);
    }

    // egates = table[captions] @ W_ihe: M=2560, N=2048, K=512
    // (LDS tiled, embedding gather fused into the A-load)
    { PairT p = {table, EM, W_iheT, EM, EM};
      gemm_lds<1, float, true><<<dim3(20, 16), 256, 0, stream>>>(
          2048, p, ZP, captions, nullptr, nullptr, egates, 2048); }

    // ---- per-step loop: 2 kernels/step ----
    for (int t = 0; t < T; ++t) {
        const int tt = t - 1;  // LSTM step computed inside K1 (t>0)
        const float* crd = (tt >= 0 && (tt & 1)) ? cbuf0 : cbuf1;
        float*       cwr = (tt >= 0 && (tt & 1)) ? cbuf1 : cbuf0;

        if (ok_fbf)
            alpha_ctx_lstm<true><<<256, 256, 0, stream>>>(
                F_bf, enc_bf, W_daT, b_da, W_fa, b_ih, b_hh, egates, part,
                crd, cwr, h_cur, h_all, ctx_all, xin, t);
        else
            alpha_ctx_lstm<false><<<256, 256, 0, stream>>>(
                F, enc_bf, W_daT, b_da, W_fa, b_ih, b_hh, egates, part,
                crd, cwr, h_cur, h_all, ctx_all, xin, t);

        gates_split4<<<dim3(16, 8, 4), 128, 0, stream>>>(xin, W_chT, part);
    }

    // final LSTM (t = T-1): T-1=19 odd -> reads cbuf0
    lstm_last<<<(B * D) / 256, 256, 0, stream>>>(
        part, egates, b_ih, b_hh, ((T - 1) & 1) ? cbuf0 : cbuf1, h_all);

    // ---- batched tail: feat for all (b,t), then logits ----
    // feat: M=2560, N=512 (streaming; small panels)
    { PairT p0 = {ctx_all, E, W_cpT, E, E};
      PairT p1 = {h_all, D, W_hpT, D, D};
      gemm_mfma<2, false, u16, 1, 4, 2, 2, true><<<dim3((B * T) / 32, EM / 128), 256, 0, stream>>>(
          EM, p0, p1, ZP, b_cp, b_hp, feat_all, EM); }

    // logits: M=2560, N=10240(pad), K=512 (LDS tiled; x=M fast so W_opT panel L2-hot)
    { PairT p = {feat_all, EM, W_opT, EM, EM};
      gemm_lds<1, float><<<dim3(20, VP2 / 128), 256, 0, stream>>>(
          V, p, ZP, nullptr, b_op, nullptr, out, V); }
}